// Round 1
// baseline (758.837 us; speedup 1.0000x reference)
//
#include <hip/hip_runtime.h>
#include <hip/hip_fp16.h>
#include <stdint.h>

#define NSEQ 256
#define LSEQ 384
#define DM   256
#define DP   128
#define NH   8
#define DHD  32
#define NL   (NSEQ*LSEQ)   /* 98304 */
#define LL   (LSEQ*LSEQ)   /* 147456 */
#define SCALE 0.17677669529663687f

typedef unsigned short u16;
typedef short bf16x8 __attribute__((ext_vector_type(8)));
typedef float f32x4 __attribute__((ext_vector_type(4)));

__device__ __forceinline__ float b2f(u16 s){
  union { uint32_t u; float f; } v; v.u = ((uint32_t)s)<<16; return v.f;
}
__device__ __forceinline__ u16 f2b(float f){
  union { float f; uint32_t u; } v; v.f = f;
  uint32_t u = v.u;
  return (u16)((u + 0x7FFFu + ((u>>16)&1u)) >> 16);
}
__device__ __forceinline__ float wsum(float x){
  #pragma unroll
  for(int o=32;o>0;o>>=1) x += __shfl_xor(x,o,64);
  return x;
}
__device__ __forceinline__ float wmax(float x){
  #pragma unroll
  for(int o=32;o>0;o>>=1) x = fmaxf(x, __shfl_xor(x,o,64));
  return x;
}
// async 16B global->LDS. LDS dest = wave-uniform base + lane*16.
__device__ __forceinline__ void gload16(const void* g, void* l){
  __builtin_amdgcn_global_load_lds((const __attribute__((address_space(1))) void*)g,
      (__attribute__((address_space(3))) void*)l, 16, 0, 0);
}

// ---------------- K1: LayerNorm(msa) -> bf16, wave per row ----------------
__global__ __launch_bounds__(256) void k_ln_msa(const float* __restrict__ msa,
    const float* __restrict__ g, const float* __restrict__ b, u16* __restrict__ out){
  int lane = threadIdx.x & 63;
  int64_t row = (int64_t)blockIdx.x*4 + (threadIdx.x>>6);
  const float4 x = *(const float4*)(msa + row*DM + lane*4);
  float s = x.x+x.y+x.z+x.w;
  float q = x.x*x.x+x.y*x.y+x.z*x.z+x.w*x.w;
  s = wsum(s); q = wsum(q);
  float mean = s*(1.0f/DM);
  float rstd = rsqrtf(q*(1.0f/DM) - mean*mean + 1e-5f);
  int c = lane*4;
  float4 gv = *(const float4*)(g+c);
  float4 bv = *(const float4*)(b+c);
  ushort4 o;
  o.x=f2b((x.x-mean)*rstd*gv.x+bv.x);
  o.y=f2b((x.y-mean)*rstd*gv.y+bv.y);
  o.z=f2b((x.z-mean)*rstd*gv.z+bv.z);
  o.w=f2b((x.w-mean)*rstd*gv.w+bv.w);
  *(ushort4*)(out + row*DM + c) = o;
}

// ---------------- K2: weight convert+transpose fp32 -> bf16 ----------------
__global__ __launch_bounds__(256) void k_wconv(const float* __restrict__ wq,
    const float* __restrict__ wk, const float* __restrict__ wv,
    const float* __restrict__ wg, const float* __restrict__ wo,
    u16* __restrict__ WTall, u16* __restrict__ WOT){
  __shared__ float tile[64][65];
  int z = blockIdx.z;
  const float* src = (z==0)?wq:(z==1)?wk:(z==2)?wv:(z==3)?wg:wo;
  u16* dst = (z<4) ? (WTall + z*DM*DM) : WOT;
  int k0 = blockIdx.x*64, n0 = blockIdx.y*64, t = threadIdx.x;
  int r = t>>4, c4 = (t&15)*4;
  #pragma unroll
  for(int it=0; it<4; it++){
    float4 v = *(const float4*)(src + (int64_t)(k0 + it*16 + r)*DM + n0 + c4);
    tile[it*16+r][c4+0]=v.x; tile[it*16+r][c4+1]=v.y;
    tile[it*16+r][c4+2]=v.z; tile[it*16+r][c4+3]=v.w;
  }
  __syncthreads();
  #pragma unroll
  for(int it=0; it<4; it++){
    int nl = it*16 + r, kl = c4;
    ushort4 o;
    o.x=f2b(tile[kl+0][nl]); o.y=f2b(tile[kl+1][nl]);
    o.z=f2b(tile[kl+2][nl]); o.w=f2b(tile[kl+3][nl]);
    *(ushort4*)(dst + (int64_t)(n0+nl)*DM + k0 + kl) = o;
  }
}

// ---------------- K3: u[l,h,c] = sum_d sw_k_w[c,h*32+d] * swq[l,h,d] -------
__global__ __launch_bounds__(256) void k_u(const u16* __restrict__ msa_n,
    const float* __restrict__ sw_q_w, const float* __restrict__ sw_q_b,
    const float* __restrict__ sw_k_w, float* __restrict__ u){
  __shared__ float tar[DM];
  __shared__ float swq[DM];
  int l = blockIdx.x, t = threadIdx.x;
  tar[t] = b2f(msa_n[(int64_t)l*DM + t]);
  __syncthreads();
  float acc = sw_q_b[t];
  for(int c=0;c<DM;c++) acc += tar[c]*sw_q_w[c*DM + t];
  swq[t] = acc * SCALE;
  __syncthreads();
  float res[NH];
  #pragma unroll
  for(int h=0;h<NH;h++){
    float a = 0.f;
    #pragma unroll
    for(int d=0;d<DHD;d+=4){
      float4 w = *(const float4*)(sw_k_w + t*DM + h*DHD + d);
      a += w.x*swq[h*DHD+d] + w.y*swq[h*DHD+d+1] + w.z*swq[h*DHD+d+2] + w.w*swq[h*DHD+d+3];
    }
    res[h]=a;
  }
  #pragma unroll
  for(int h=0;h<NH;h++) u[((int64_t)l*NH + h)*DM + t] = res[h];
}

// ---------------- K4: sw_logits + softmax over n -> seq_weight[n,l,h] ------
__global__ __launch_bounds__(256) void k_seqw(const u16* __restrict__ msa_n,
    const float* __restrict__ u, float* __restrict__ sw){
  __shared__ float ul[NH*DM];
  __shared__ float lg[NH*256];
  __shared__ float mx[NH], sm[NH];
  int l = blockIdx.x, t = threadIdx.x;
  #pragma unroll
  for(int h=0;h<NH;h++) ul[h*DM+t] = u[((int64_t)l*NH+h)*DM + t];
  __syncthreads();
  float acc[NH] = {};
  const u16* row = msa_n + ((int64_t)t*LSEQ + l)*DM;   // n = t
  for(int c=0;c<DM;c+=4){
    ushort4 xv = *(const ushort4*)(row + c);
    float x0=b2f(xv.x), x1=b2f(xv.y), x2=b2f(xv.z), x3=b2f(xv.w);
    #pragma unroll
    for(int h=0;h<NH;h++)
      acc[h] += x0*ul[h*DM+c] + x1*ul[h*DM+c+1] + x2*ul[h*DM+c+2] + x3*ul[h*DM+c+3];
  }
  #pragma unroll
  for(int h=0;h<NH;h++) lg[h*256+t] = acc[h];
  __syncthreads();
  int wv = t>>6, ln = t&63;
  for(int h=wv; h<NH; h+=4){
    float a=lg[h*256+ln], b=lg[h*256+ln+64], c=lg[h*256+ln+128], d=lg[h*256+ln+192];
    float m = wmax(fmaxf(fmaxf(a,b),fmaxf(c,d)));
    float e = __expf(a-m)+__expf(b-m)+__expf(c-m)+__expf(d-m);
    e = wsum(e);
    if(ln==0){ mx[h]=m; sm[h]=1.f/e; }
  }
  __syncthreads();
  float o[NH];
  #pragma unroll
  for(int h=0;h<NH;h++) o[h] = __expf(acc[h]-mx[h])*sm[h];
  float* dst = sw + ((int64_t)t*LSEQ + l)*NH;
  *(float4*)dst     = make_float4(o[0],o[1],o[2],o[3]);
  *(float4*)(dst+4) = make_float4(o[4],o[5],o[6],o[7]);
}

// ---------------- K5: bias[h][q][k] = LN(pair[q,k,:]) @ wb -----------------
__global__ __launch_bounds__(256) void k_bias(const float* __restrict__ pair,
    const float* __restrict__ g, const float* __restrict__ b,
    const float* __restrict__ wb, float* __restrict__ bias){
  int64_t row = (int64_t)blockIdx.x*256 + threadIdx.x;   // over L*L
  const float* pr = pair + row*DP;
  uint2 xs[32];                       // 128 channels as packed fp16
  float s = 0.f, q = 0.f;
  #pragma unroll
  for(int i=0;i<32;i++){
    float4 v = *(const float4*)(pr + i*4);
    s += v.x+v.y+v.z+v.w;
    q += v.x*v.x+v.y*v.y+v.z*v.z+v.w*v.w;
    __half2 p0 = __floats2half2_rn(v.x, v.y);
    __half2 p1 = __floats2half2_rn(v.z, v.w);
    xs[i].x = *(const uint32_t*)&p0;
    xs[i].y = *(const uint32_t*)&p1;
  }
  float mean = s*(1.f/DP);
  float rstd = rsqrtf(q*(1.f/DP) - mean*mean + 1e-5f);
  float acc[NH] = {};
  #pragma unroll
  for(int i=0;i<32;i++){
    __half2 p0 = *(const __half2*)&xs[i].x;
    __half2 p1 = *(const __half2*)&xs[i].y;
    float2 f0 = __half22float2(p0);
    float2 f1 = __half22float2(p1);
    float xv[4] = {f0.x, f0.y, f1.x, f1.y};
    #pragma unroll
    for(int c4=0;c4<4;c4++){
      int c = i*4 + c4;
      float y = (xv[c4]-mean)*rstd*g[c] + b[c];
      #pragma unroll
      for(int h=0;h<NH;h++) acc[h] += y*wb[c*NH+h];
    }
  }
  #pragma unroll
  for(int h=0;h<NH;h++) bias[(int64_t)h*LL + row] = acc[h];
}

// ==================== MFMA GEMM core (shared idioms) ========================
// 128x128 tile, 4 waves (2x2 of 64x64), BK=64, 16x16x32 bf16 MFMA.
// LDS rows: 64 bf16 = 8 chunks of 16B; logical chunk g stored at phys g^(row&7).
// NEW (this round): 2-phase double-buffered prefetch — STAGE(r+1) into buf^1
// is issued BEFORE computing buf, ONE __syncthreads() per round. The barrier's
// implicit vmcnt(0) drains loads that flew during the MFMA phase instead of
// being waited on cold. Safe with plain __syncthreads(): buf^1 is only
// written after the barrier that ended all ds_reads of it.

// ---------------- K6: fused projection, one block per 128-row strip --------
// Loops all 8 col-tiles (q|k|v|g x2) so the A-tile is re-read from L2, not HBM.
__global__ __launch_bounds__(256) void k_projf(const u16* __restrict__ A,
    const u16* __restrict__ WT, u16* __restrict__ qb, u16* __restrict__ kb,
    u16* __restrict__ gbuf, u16* __restrict__ VT,
    const float* __restrict__ sw, const float* __restrict__ bg){
  __shared__ short As[2][128*64];
  __shared__ short Bs[2][128*64];
  int t = threadIdx.x;
  int w = t>>6, lane = t&63, ln15 = lane&15, quad = lane>>4;
  int rIn = lane>>3, cch = lane&7;
  int mw = (w>>1)*64, nw = (w&1)*64;
  int bx = blockIdx.x;              // 0..767 row tile
  int64_t r0 = (int64_t)bx*128;
  int g = cch ^ rIn;                // swizzled logical chunk (const per lane)

  auto PSTAGE = [&](int r, int bsel){   // round r: nt=r>>2, it=r&3
    int n0_ = (r>>2)*128, k0_ = (r&3)*64;
    #pragma unroll
    for(int ti=0; ti<4; ti++){
      int row = w*32 + ti*8 + rIn;
      gload16(A  + (r0+row)*DM + k0_ + g*8, &As[bsel][(w*32+ti*8)*64]);
      gload16(WT + (int64_t)(n0_+row)*DM + k0_ + g*8, &Bs[bsel][(w*32+ti*8)*64]);
    }
  };

  f32x4 acc[4][4] = {};
  PSTAGE(0, 0);
  __syncthreads();
  for(int r=0; r<32; r++){
    int buf = r&1;
    if(r<31) PSTAGE(r+1, buf^1);
    #pragma unroll
    for(int kk=0;kk<2;kk++){
      int p = (kk*4+quad) ^ (lane&7);
      bf16x8 af[4], bfv[4];
      #pragma unroll
      for(int i=0;i<4;i++) af[i]  = *(const bf16x8*)&As[buf][(mw+i*16+ln15)*64 + p*8];
      #pragma unroll
      for(int j=0;j<4;j++) bfv[j] = *(const bf16x8*)&Bs[buf][(nw+j*16+ln15)*64 + p*8];
      #pragma unroll
      for(int i=0;i<4;i++)
        #pragma unroll
        for(int j=0;j<4;j++)
          acc[i][j] = __builtin_amdgcn_mfma_f32_16x16x32_bf16(af[i], bfv[j], acc[i][j], 0,0,0);
    }
    if((r&3)==3){
      int nt = r>>2;
      int mode = nt>>1;
      int cmb = (nt&1)*128 + nw;      // within-mode col base for this wave
      if(mode==2){
        // V: write transposed VT[h][s][d][kpos], 4 regs = 4 consecutive kpos
        int s = bx/3, kb3 = (bx%3)*128 + mw;
        #pragma unroll
        for(int j=0;j<4;j++){
          int cm = cmb + j*16 + ln15;
          int hh = cm>>5, d = cm&31;
          #pragma unroll
          for(int i=0;i<4;i++){
            int kpos0 = kb3 + i*16 + quad*4;
            ushort4 o;
            o.x=f2b(acc[i][j][0]); o.y=f2b(acc[i][j][1]);
            o.z=f2b(acc[i][j][2]); o.w=f2b(acc[i][j][3]);
            *(ushort4*)(VT + ((int64_t)(hh*NSEQ+s)*DHD + d)*LSEQ + kpos0) = o;
          }
        }
      } else {
        u16* dst = (mode==0)?qb:(mode==1)?kb:gbuf;
        float bgv[4];
        if(mode==3){
          #pragma unroll
          for(int j=0;j<4;j++) bgv[j] = bg[cmb + j*16 + ln15];
        }
        #pragma unroll
        for(int i=0;i<4;i++)
          #pragma unroll
          for(int reg=0;reg<4;reg++){
            int64_t rr = r0 + mw + i*16 + quad*4 + reg;
            #pragma unroll
            for(int j=0;j<4;j++){
              int cm = cmb + j*16 + ln15;
              float v = acc[i][j][reg];
              if(mode==0)      v *= sw[rr*NH + (cm>>5)];
              else if(mode==1) v *= SCALE;
              else             v = 1.f/(1.f+__expf(-(v+bgv[j])));
              dst[rr*DM + cm] = f2b(v);
            }
          }
      }
      #pragma unroll
      for(int i=0;i<4;i++)
        #pragma unroll
        for(int j=0;j<4;j++) acc[i][j] = (f32x4){0.f,0.f,0.f,0.f};
    }
    __syncthreads();
  }
}

// ---------------- K7: scores slab sc: S[h][q][k] += Q.K over s-chunk -------
__global__ __launch_bounds__(256) void k_scores(const u16* __restrict__ Q,
    const u16* __restrict__ K, float* __restrict__ scores){
  __shared__ short As[2][128*64];
  __shared__ short Bs[2][128*64];
  int t = threadIdx.x;
  int w = t>>6, lane = t&63, ln15 = lane&15, quad = lane>>4;
  int rIn = lane>>3, cch = lane&7;
  int mw = (w>>1)*64, nw = (w&1)*64;
  int q0 = blockIdx.x*128, k0t = blockIdx.y*128;
  int h = blockIdx.z>>2, sc = blockIdx.z&3;
  int g = cch ^ rIn;
  int s_off = g>>2, d16 = g&3;

  auto PSTAGE = [&](int i2, int bsel){
    int sb = sc*64 + i2*2 + s_off;
    #pragma unroll
    for(int ti=0; ti<4; ti++){
      int row = w*32 + ti*8 + rIn;
      gload16(Q + ((int64_t)sb*LSEQ + q0 + row)*DM + h*DHD + d16*8, &As[bsel][(w*32+ti*8)*64]);
      gload16(K + ((int64_t)sb*LSEQ + k0t + row)*DM + h*DHD + d16*8, &Bs[bsel][(w*32+ti*8)*64]);
    }
  };

  f32x4 acc[4][4] = {};
  PSTAGE(0, 0);
  __syncthreads();
  for(int i2=0; i2<32; i2++){
    int buf = i2&1;
    if(i2<31) PSTAGE(i2+1, buf^1);
    #pragma unroll
    for(int kk=0;kk<2;kk++){
      int p = (kk*4+quad) ^ (lane&7);
      bf16x8 af[4], bfv[4];
      #pragma unroll
      for(int i=0;i<4;i++) af[i]  = *(const bf16x8*)&As[buf][(mw+i*16+ln15)*64 + p*8];
      #pragma unroll
      for(int j=0;j<4;j++) bfv[j] = *(const bf16x8*)&Bs[buf][(nw+j*16+ln15)*64 + p*8];
      #pragma unroll
      for(int i=0;i<4;i++)
        #pragma unroll
        for(int j=0;j<4;j++)
          acc[i][j] = __builtin_amdgcn_mfma_f32_16x16x32_bf16(af[i], bfv[j], acc[i][j], 0,0,0);
    }
    __syncthreads();
  }
  int64_t slab = (int64_t)sc*NH*LL;
  #pragma unroll
  for(int i=0;i<4;i++)
    #pragma unroll
    for(int reg=0;reg<4;reg++){
      int q = q0 + mw + i*16 + quad*4 + reg;
      float* rp = scores + slab + ((int64_t)h*LSEQ + q)*LSEQ + k0t + nw + ln15;
      #pragma unroll
      for(int j=0;j<4;j++) rp[j*16] = acc[i][j][reg];
    }
}

// ---------------- K8: sum slabs + bias, softmax over k -> P bf16 -----------
__global__ __launch_bounds__(128) void k_softmax(const float* __restrict__ scores,
    const float* __restrict__ bias, u16* __restrict__ Pb){
  int hq = blockIdx.x, t = threadIdx.x;
  int64_t base = (int64_t)hq*LSEQ;
  float v[3];
  #pragma unroll
  for(int i=0;i<3;i++){
    int k = t + i*128;
    float x = bias[base+k];
    x += scores[base+k];
    x += scores[(int64_t)1*NH*LL + base + k];
    x += scores[(int64_t)2*NH*LL + base + k];
    x += scores[(int64_t)3*NH*LL + base + k];
    v[i]=x;
  }
  __shared__ float red[2], red2[2];
  int wv=t>>6, ln=t&63;
  float m = fmaxf(fmaxf(v[0],v[1]),v[2]);
  m = wmax(m);
  if(ln==0) red[wv]=m;
  __syncthreads();
  m = fmaxf(red[0],red[1]);
  float e = __expf(v[0]-m)+__expf(v[1]-m)+__expf(v[2]-m);
  e = wsum(e);
  if(ln==0) red2[wv]=e;
  __syncthreads();
  float inv = 1.f/(red2[0]+red2[1]);
  #pragma unroll
  for(int i=0;i<3;i++) Pb[base + t + i*128] = f2b(__expf(v[i]-m)*inv);
}

// ---------------- K9: PV. C[(s,d)][q] = sum_k VT[h][(s,d)][k] * P[h][q][k] --
__global__ __launch_bounds__(256) void k_pv(const u16* __restrict__ VT,
    const u16* __restrict__ Pb, const u16* __restrict__ gbuf,
    u16* __restrict__ attn){
  __shared__ short As[2][128*64];
  __shared__ short Bs[2][128*64];
  int t = threadIdx.x;
  int w = t>>6, lane = t&63, ln15 = lane&15, quad = lane>>4;
  int rIn = lane>>3, cch = lane&7;
  int mw = (w>>1)*64, nw = (w&1)*64;
  int mx = blockIdx.x, ny = blockIdx.y, h = blockIdx.z;
  int g = cch ^ rIn;

  auto PSTAGE = [&](int it, int bsel){
    int k0 = it*64;
    #pragma unroll
    for(int ti=0; ti<4; ti++){
      int row = w*32 + ti*8 + rIn;
      gload16(VT + ((int64_t)h*8192 + mx*128 + row)*LSEQ + k0 + g*8, &As[bsel][(w*32+ti*8)*64]);
      gload16(Pb + ((int64_t)h*LSEQ + ny*128 + row)*LSEQ + k0 + g*8, &Bs[bsel][(w*32+ti*8)*64]);
    }
  };

  f32x4 acc[4][4] = {};
  PSTAGE(0, 0);
  __syncthreads();
  for(int it=0; it<6; it++){
    int buf = it&1;
    if(it<5) PSTAGE(it+1, buf^1);
    #pragma unroll
    for(int kk=0;kk<2;kk++){
      int p = (kk*4+quad) ^ (lane&7);
      bf16x8 af[4], bfv[4];
      #pragma unroll
      for(int i=0;i<4;i++) af[i]  = *(const bf16x8*)&As[buf][(mw+i*16+ln15)*64 + p*8];
      #pragma unroll
      for(int j=0;j<4;j++) bfv[j] = *(const bf16x8*)&Bs[buf][(nw+j*16+ln15)*64 + p*8];
      #pragma unroll
      for(int i=0;i<4;i++)
        #pragma unroll
        for(int j=0;j<4;j++)
          acc[i][j] = __builtin_amdgcn_mfma_f32_16x16x32_bf16(af[i], bfv[j], acc[i][j], 0,0,0);
    }
    __syncthreads();
  }
  #pragma unroll
  for(int i=0;i<4;i++){
    int m0 = mx*128 + mw + i*16 + quad*4;
    int s = m0>>5, d0 = m0&31;
    #pragma unroll
    for(int j=0;j<4;j++){
      int q = ny*128 + nw + j*16 + ln15;
      int64_t base = ((int64_t)s*LSEQ + q)*DM + h*DHD + d0;
      ushort4 gv = *(const ushort4*)(gbuf + base);
      ushort4 o;
      o.x = f2b(acc[i][j][0]*b2f(gv.x));
      o.y = f2b(acc[i][j][1]*b2f(gv.y));
      o.z = f2b(acc[i][j][2]*b2f(gv.z));
      o.w = f2b(acc[i][j][3]*b2f(gv.w));
      *(ushort4*)(attn + base) = o;
    }
  }
}

// ---------------- K10: out = attnout @ wo + bo (fp32 out) ------------------
__global__ __launch_bounds__(256) void k_final(const u16* __restrict__ A,
    const u16* __restrict__ WOT, const float* __restrict__ bo,
    float* __restrict__ out){
  __shared__ short As[2][128*64];
  __shared__ short Bs[2][128*64];
  int t = threadIdx.x;
  int w = t>>6, lane = t&63, ln15 = lane&15, quad = lane>>4;
  int rIn = lane>>3, cch = lane&7;
  int mw = (w>>1)*64, nw = (w&1)*64;
  int n0 = blockIdx.x*128;
  int64_t r0 = (int64_t)blockIdx.y*128;
  int g = cch ^ rIn;

  auto PSTAGE = [&](int it, int bsel){
    int k0 = it*64;
    #pragma unroll
    for(int ti=0; ti<4; ti++){
      int row = w*32 + ti*8 + rIn;
      gload16(A   + (r0+row)*DM + k0 + g*8, &As[bsel][(w*32+ti*8)*64]);
      gload16(WOT + (int64_t)(n0+row)*DM + k0 + g*8, &Bs[bsel][(w*32+ti*8)*64]);
    }
  };

  f32x4 acc[4][4] = {};
  PSTAGE(0, 0);
  __syncthreads();
  for(int it=0; it<4; it++){
    int buf = it&1;
    if(it<3) PSTAGE(it+1, buf^1);
    #pragma unroll
    for(int kk=0;kk<2;kk++){
      int p = (kk*4+quad) ^ (lane&7);
      bf16x8 af[4], bfv[4];
      #pragma unroll
      for(int i=0;i<4;i++) af[i]  = *(const bf16x8*)&As[buf][(mw+i*16+ln15)*64 + p*8];
      #pragma unroll
      for(int j=0;j<4;j++) bfv[j] = *(const bf16x8*)&Bs[buf][(nw+j*16+ln15)*64 + p*8];
      #pragma unroll
      for(int i=0;i<4;i++)
        #pragma unroll
        for(int j=0;j<4;j++)
          acc[i][j] = __builtin_amdgcn_mfma_f32_16x16x32_bf16(af[i], bfv[j], acc[i][j], 0,0,0);
    }
    __syncthreads();
  }
  float bv[4];
  #pragma unroll
  for(int j=0;j<4;j++) bv[j] = bo[n0 + nw + j*16 + ln15];
  #pragma unroll
  for(int i=0;i<4;i++)
    #pragma unroll
    for(int reg=0;reg<4;reg++){
      int64_t r = r0 + mw + i*16 + quad*4 + reg;
      float* rp = out + r*DM + n0 + nw + ln15;
      #pragma unroll
      for(int j=0;j<4;j++) rp[j*16] = acc[i][j][reg] + bv[j];
    }
}

extern "C" void kernel_launch(void* const* d_in, const int* in_sizes, int n_in,
                              void* d_out, int out_size, void* d_ws, size_t ws_size,
                              hipStream_t stream){
  const float* msa    = (const float*)d_in[0];
  const float* pair   = (const float*)d_in[1];
  const float* lmg    = (const float*)d_in[2];
  const float* lmb    = (const float*)d_in[3];
  const float* lpg    = (const float*)d_in[4];
  const float* lpb    = (const float*)d_in[5];
  const float* sw_q_w = (const float*)d_in[6];
  const float* sw_q_b = (const float*)d_in[7];
  const float* sw_k_w = (const float*)d_in[8];
  // d_in[9] = sw_k_b: constant over n, cancels in softmax over n.
  const float* wq     = (const float*)d_in[10];
  const float* wk     = (const float*)d_in[11];
  const float* wv     = (const float*)d_in[12];
  const float* wb     = (const float*)d_in[13];
  const float* wg     = (const float*)d_in[14];
  const float* bg     = (const float*)d_in[15];
  const float* wo     = (const float*)d_in[16];
  const float* bo     = (const float*)d_in[17];
  float* out = (float*)d_out;

  // workspace layout (~285 MB)
  u16* msa_n = (u16*)d_ws;                       // [NL][256] bf16
  u16* qb    = msa_n + (int64_t)NL*DM;
  u16* kb    = qb + (int64_t)NL*DM;
  u16* gbuf  = kb + (int64_t)NL*DM;
  u16* VT    = gbuf + (int64_t)NL*DM;            // [8][256][32][384] bf16
  u16* Pb    = VT + (int64_t)NL*DM;              // [8][384][384] bf16
  u16* WTall = Pb + (int64_t)NH*LSEQ*LSEQ;       // [1024][256] bf16
  u16* WOT   = WTall + 1024*DM;                  // [256][256] bf16
  float* u_buf = (float*)(WOT + DM*DM);          // [384][8][256] f32
  float* sw  = u_buf + (int64_t)LSEQ*NH*DM;      // [256*384][8] f32
  float* bias = sw + (int64_t)NL*NH;             // [8][384][384] f32
  float* scores = bias + (int64_t)NH*LL;         // 4 slabs [8][384][384] f32
  u16* attnout = msa_n;                          // alias: msa_n dead after proj

  k_ln_msa<<<NL/4, 256, 0, stream>>>(msa, lmg, lmb, msa_n);
  k_wconv<<<dim3(4,4,5), 256, 0, stream>>>(wq, wk, wv, wg, wo, WTall, WOT);
  k_u<<<LSEQ, 256, 0, stream>>>(msa_n, sw_q_w, sw_q_b, sw_k_w, u_buf);
  k_seqw<<<LSEQ, 256, 0, stream>>>(msa_n, u_buf, sw);
  k_bias<<<LL/256, 256, 0, stream>>>(pair, lpg, lpb, wb, bias);
  k_projf<<<dim3(NL/128), 256, 0, stream>>>(msa_n, WTall, qb, kb, gbuf, VT, sw, bg);
  k_scores<<<dim3(3,3,32), 256, 0, stream>>>(qb, kb, scores);
  k_softmax<<<NH*LSEQ, 128, 0, stream>>>(scores, bias, Pb);
  k_pv<<<dim3(64,3,NH), 256, 0, stream>>>(VT, Pb, gbuf, attnout);
  k_final<<<dim3(2, NL/128), 256, 0, stream>>>(attnout, WOT, bo, out);
}

// Round 2
// 742.022 us; speedup vs baseline: 1.0227x; 1.0227x over previous
//
#include <hip/hip_runtime.h>
#include <hip/hip_fp16.h>
#include <stdint.h>

#define NSEQ 256
#define LSEQ 384
#define DM   256
#define DP   128
#define NH   8
#define DHD  32
#define NL   (NSEQ*LSEQ)   /* 98304 */
#define LL   (LSEQ*LSEQ)   /* 147456 */
#define SCALE 0.17677669529663687f

typedef unsigned short u16;
typedef short bf16x8 __attribute__((ext_vector_type(8)));
typedef float f32x4 __attribute__((ext_vector_type(4)));

__device__ __forceinline__ float b2f(u16 s){
  union { uint32_t u; float f; } v; v.u = ((uint32_t)s)<<16; return v.f;
}
__device__ __forceinline__ u16 f2b(float f){
  union { float f; uint32_t u; } v; v.f = f;
  uint32_t u = v.u;
  return (u16)((u + 0x7FFFu + ((u>>16)&1u)) >> 16);
}
__device__ __forceinline__ float wsum(float x){
  #pragma unroll
  for(int o=32;o>0;o>>=1) x += __shfl_xor(x,o,64);
  return x;
}
__device__ __forceinline__ float wmax(float x){
  #pragma unroll
  for(int o=32;o>0;o>>=1) x = fmaxf(x, __shfl_xor(x,o,64));
  return x;
}
// async 16B global->LDS. LDS dest = wave-uniform base + lane*16.
__device__ __forceinline__ void gload16(const void* g, void* l){
  __builtin_amdgcn_global_load_lds((const __attribute__((address_space(1))) void*)g,
      (__attribute__((address_space(3))) void*)l, 16, 0, 0);
}

// ---------------- K1: LayerNorm(msa) -> bf16, wave per row ----------------
__global__ __launch_bounds__(256) void k_ln_msa(const float* __restrict__ msa,
    const float* __restrict__ g, const float* __restrict__ b, u16* __restrict__ out){
  int lane = threadIdx.x & 63;
  int64_t row = (int64_t)blockIdx.x*4 + (threadIdx.x>>6);
  const float4 x = *(const float4*)(msa + row*DM + lane*4);
  float s = x.x+x.y+x.z+x.w;
  float q = x.x*x.x+x.y*x.y+x.z*x.z+x.w*x.w;
  s = wsum(s); q = wsum(q);
  float mean = s*(1.0f/DM);
  float rstd = rsqrtf(q*(1.0f/DM) - mean*mean + 1e-5f);
  int c = lane*4;
  float4 gv = *(const float4*)(g+c);
  float4 bv = *(const float4*)(b+c);
  ushort4 o;
  o.x=f2b((x.x-mean)*rstd*gv.x+bv.x);
  o.y=f2b((x.y-mean)*rstd*gv.y+bv.y);
  o.z=f2b((x.z-mean)*rstd*gv.z+bv.z);
  o.w=f2b((x.w-mean)*rstd*gv.w+bv.w);
  *(ushort4*)(out + row*DM + c) = o;
}

// ---------------- K2: weight convert+transpose fp32 -> bf16 ----------------
__global__ __launch_bounds__(256) void k_wconv(const float* __restrict__ wq,
    const float* __restrict__ wk, const float* __restrict__ wv,
    const float* __restrict__ wg, const float* __restrict__ wo,
    u16* __restrict__ WTall, u16* __restrict__ WOT){
  __shared__ float tile[64][65];
  int z = blockIdx.z;
  const float* src = (z==0)?wq:(z==1)?wk:(z==2)?wv:(z==3)?wg:wo;
  u16* dst = (z<4) ? (WTall + z*DM*DM) : WOT;
  int k0 = blockIdx.x*64, n0 = blockIdx.y*64, t = threadIdx.x;
  int r = t>>4, c4 = (t&15)*4;
  #pragma unroll
  for(int it=0; it<4; it++){
    float4 v = *(const float4*)(src + (int64_t)(k0 + it*16 + r)*DM + n0 + c4);
    tile[it*16+r][c4+0]=v.x; tile[it*16+r][c4+1]=v.y;
    tile[it*16+r][c4+2]=v.z; tile[it*16+r][c4+3]=v.w;
  }
  __syncthreads();
  #pragma unroll
  for(int it=0; it<4; it++){
    int nl = it*16 + r, kl = c4;
    ushort4 o;
    o.x=f2b(tile[kl+0][nl]); o.y=f2b(tile[kl+1][nl]);
    o.z=f2b(tile[kl+2][nl]); o.w=f2b(tile[kl+3][nl]);
    *(ushort4*)(dst + (int64_t)(n0+nl)*DM + k0 + kl) = o;
  }
}

// ---------------- K3: u[l,h,c] = sum_d sw_k_w[c,h*32+d] * swq[l,h,d] -------
__global__ __launch_bounds__(256) void k_u(const u16* __restrict__ msa_n,
    const float* __restrict__ sw_q_w, const float* __restrict__ sw_q_b,
    const float* __restrict__ sw_k_w, float* __restrict__ u){
  __shared__ float tar[DM];
  __shared__ float swq[DM];
  int l = blockIdx.x, t = threadIdx.x;
  tar[t] = b2f(msa_n[(int64_t)l*DM + t]);
  __syncthreads();
  float acc = sw_q_b[t];
  for(int c=0;c<DM;c++) acc += tar[c]*sw_q_w[c*DM + t];
  swq[t] = acc * SCALE;
  __syncthreads();
  float res[NH];
  #pragma unroll
  for(int h=0;h<NH;h++){
    float a = 0.f;
    #pragma unroll
    for(int d=0;d<DHD;d+=4){
      float4 w = *(const float4*)(sw_k_w + t*DM + h*DHD + d);
      a += w.x*swq[h*DHD+d] + w.y*swq[h*DHD+d+1] + w.z*swq[h*DHD+d+2] + w.w*swq[h*DHD+d+3];
    }
    res[h]=a;
  }
  #pragma unroll
  for(int h=0;h<NH;h++) u[((int64_t)l*NH + h)*DM + t] = res[h];
}

// ---------------- K4: sw_logits + softmax over n -> seq_weight[n,l,h] ------
__global__ __launch_bounds__(256) void k_seqw(const u16* __restrict__ msa_n,
    const float* __restrict__ u, float* __restrict__ sw){
  __shared__ float ul[NH*DM];
  __shared__ float lg[NH*256];
  __shared__ float mx[NH], sm[NH];
  int l = blockIdx.x, t = threadIdx.x;
  #pragma unroll
  for(int h=0;h<NH;h++) ul[h*DM+t] = u[((int64_t)l*NH+h)*DM + t];
  __syncthreads();
  float acc[NH] = {};
  const u16* row = msa_n + ((int64_t)t*LSEQ + l)*DM;   // n = t
  for(int c=0;c<DM;c+=4){
    ushort4 xv = *(const ushort4*)(row + c);
    float x0=b2f(xv.x), x1=b2f(xv.y), x2=b2f(xv.z), x3=b2f(xv.w);
    #pragma unroll
    for(int h=0;h<NH;h++)
      acc[h] += x0*ul[h*DM+c] + x1*ul[h*DM+c+1] + x2*ul[h*DM+c+2] + x3*ul[h*DM+c+3];
  }
  #pragma unroll
  for(int h=0;h<NH;h++) lg[h*256+t] = acc[h];
  __syncthreads();
  int wv = t>>6, ln = t&63;
  for(int h=wv; h<NH; h+=4){
    float a=lg[h*256+ln], b=lg[h*256+ln+64], c=lg[h*256+ln+128], d=lg[h*256+ln+192];
    float m = wmax(fmaxf(fmaxf(a,b),fmaxf(c,d)));
    float e = __expf(a-m)+__expf(b-m)+__expf(c-m)+__expf(d-m);
    e = wsum(e);
    if(ln==0){ mx[h]=m; sm[h]=1.f/e; }
  }
  __syncthreads();
  float o[NH];
  #pragma unroll
  for(int h=0;h<NH;h++) o[h] = __expf(acc[h]-mx[h])*sm[h];
  float* dst = sw + ((int64_t)t*LSEQ + l)*NH;
  *(float4*)dst     = make_float4(o[0],o[1],o[2],o[3]);
  *(float4*)(dst+4) = make_float4(o[4],o[5],o[6],o[7]);
}

// ---------------- K5: bias[h][q][k] = LN(pair[q,k,:]) @ wb -----------------
__global__ __launch_bounds__(256) void k_bias(const float* __restrict__ pair,
    const float* __restrict__ g, const float* __restrict__ b,
    const float* __restrict__ wb, float* __restrict__ bias){
  int64_t row = (int64_t)blockIdx.x*256 + threadIdx.x;   // over L*L
  const float* pr = pair + row*DP;
  uint2 xs[32];                       // 128 channels as packed fp16
  float s = 0.f, q = 0.f;
  #pragma unroll
  for(int i=0;i<32;i++){
    float4 v = *(const float4*)(pr + i*4);
    s += v.x+v.y+v.z+v.w;
    q += v.x*v.x+v.y*v.y+v.z*v.z+v.w*v.w;
    __half2 p0 = __floats2half2_rn(v.x, v.y);
    __half2 p1 = __floats2half2_rn(v.z, v.w);
    xs[i].x = *(const uint32_t*)&p0;
    xs[i].y = *(const uint32_t*)&p1;
  }
  float mean = s*(1.f/DP);
  float rstd = rsqrtf(q*(1.f/DP) - mean*mean + 1e-5f);
  float acc[NH] = {};
  #pragma unroll
  for(int i=0;i<32;i++){
    __half2 p0 = *(const __half2*)&xs[i].x;
    __half2 p1 = *(const __half2*)&xs[i].y;
    float2 f0 = __half22float2(p0);
    float2 f1 = __half22float2(p1);
    float xv[4] = {f0.x, f0.y, f1.x, f1.y};
    #pragma unroll
    for(int c4=0;c4<4;c4++){
      int c = i*4 + c4;
      float y = (xv[c4]-mean)*rstd*g[c] + b[c];
      #pragma unroll
      for(int h=0;h<NH;h++) acc[h] += y*wb[c*NH+h];
    }
  }
  #pragma unroll
  for(int h=0;h<NH;h++) bias[(int64_t)h*LL + row] = acc[h];
}

// ==================== MFMA cores ============================================
// k_projf/k_final: A-strip (128x256 bf16, 64KB) staged ONCE into LDS with
// pre-swizzled source (chunk c of row r stored at phys c^(r&7)); ONE barrier;
// then barrier-free main loop: B (weight matrix, L2-resident) loaded directly
// global->registers, fully coalesced (16 rows x 64B per instr). No LDS write
// hazards -> no vmcnt drains -> compiler free to prefetch loads across MFMAs
// and epilogue stores.

// ---------------- K6: fused projection, one block per 128-row strip --------
__global__ __launch_bounds__(256) void k_projf(const u16* __restrict__ A,
    const u16* __restrict__ WT, u16* __restrict__ qb, u16* __restrict__ kb,
    u16* __restrict__ gbuf, u16* __restrict__ VT,
    const float* __restrict__ sw, const float* __restrict__ bg){
  __shared__ short As[128*256];        // 64 KB
  int t = threadIdx.x;
  int w = t>>6, lane = t&63, ln15 = lane&15, quad = lane>>4;
  int mw = (w>>1)*64, nw = (w&1)*64;
  int bx = blockIdx.x;                 // 0..767 row strip
  int64_t r0 = (int64_t)bx*128;

  // ---- stage A strip once: 64 gload16 (1KB each = 2 rows), 16 per wave ----
  {
    int rowl = lane>>5;                // 0..1 within the 2-row chunk
    int pc = lane&31;                  // phys 16B chunk within 512B row
    #pragma unroll
    for(int m=0;m<16;m++){
      int q = w*16+m;
      int row = 2*q + rowl;
      int gch = pc ^ (row&7);          // logical chunk that belongs at phys pc
      gload16(A + (r0+row)*DM + gch*8, &As[q*512]);
    }
  }
  __syncthreads();                     // only barrier in the kernel

  for(int nt=0; nt<8; nt++){
    int n0 = nt*128;
    f32x4 acc[4][4] = {};
    #pragma unroll
    for(int ks=0; ks<8; ks++){         // K-slice of 32
      bf16x8 af[4], bfv[4];
      #pragma unroll
      for(int j=0;j<4;j++)
        bfv[j] = *(const bf16x8*)(WT + (int64_t)(n0+nw+j*16+ln15)*DM + ks*32 + quad*8);
      #pragma unroll
      for(int i=0;i<4;i++){
        int row = mw+i*16+ln15;
        af[i] = *(const bf16x8*)&As[row*256 + (((ks*4+quad) ^ (ln15&7)))*8];
      }
      #pragma unroll
      for(int i=0;i<4;i++)
        #pragma unroll
        for(int j=0;j<4;j++)
          acc[i][j] = __builtin_amdgcn_mfma_f32_16x16x32_bf16(af[i], bfv[j], acc[i][j], 0,0,0);
    }
    // ---- epilogue for this col-tile ----
    int mode = nt>>1;
    int cmb = (nt&1)*128 + nw;
    if(mode==2){
      // V: write transposed VT[h][s][d][kpos], 4 regs = 4 consecutive kpos
      int s = bx/3, kb3 = (bx%3)*128 + mw;
      #pragma unroll
      for(int j=0;j<4;j++){
        int cm = cmb + j*16 + ln15;
        int hh = cm>>5, d = cm&31;
        #pragma unroll
        for(int i=0;i<4;i++){
          int kpos0 = kb3 + i*16 + quad*4;
          ushort4 o;
          o.x=f2b(acc[i][j][0]); o.y=f2b(acc[i][j][1]);
          o.z=f2b(acc[i][j][2]); o.w=f2b(acc[i][j][3]);
          *(ushort4*)(VT + ((int64_t)(hh*NSEQ+s)*DHD + d)*LSEQ + kpos0) = o;
        }
      }
    } else {
      u16* dst = (mode==0)?qb:(mode==1)?kb:gbuf;
      float bgv[4];
      if(mode==3){
        #pragma unroll
        for(int j=0;j<4;j++) bgv[j] = bg[cmb + j*16 + ln15];
      }
      #pragma unroll
      for(int i=0;i<4;i++)
        #pragma unroll
        for(int reg=0;reg<4;reg++){
          int64_t rr = r0 + mw + i*16 + quad*4 + reg;
          #pragma unroll
          for(int j=0;j<4;j++){
            int cm = cmb + j*16 + ln15;
            float v = acc[i][j][reg];
            if(mode==0)      v *= sw[rr*NH + (cm>>5)];
            else if(mode==1) v *= SCALE;
            else             v = 1.f/(1.f+__expf(-(v+bgv[j])));
            dst[rr*DM + cm] = f2b(v);
          }
        }
    }
  }
}

// ---------------- K7: scores slab sc: S[h][q][k] += Q.K over s-chunk -------
__global__ __launch_bounds__(256) void k_scores(const u16* __restrict__ Q,
    const u16* __restrict__ K, float* __restrict__ scores){
  __shared__ short As[128*64];
  __shared__ short Bs[128*64];
  int t = threadIdx.x;
  int w = t>>6, lane = t&63, ln15 = lane&15, quad = lane>>4;
  int rIn = lane>>3, cch = lane&7;
  int mw = (w>>1)*64, nw = (w&1)*64;
  int q0 = blockIdx.x*128, k0t = blockIdx.y*128;
  int h = blockIdx.z>>2, sc = blockIdx.z&3;
  int g = cch ^ rIn;
  int s_off = g>>2, d16 = g&3;
  f32x4 acc[4][4] = {};
  for(int i2=0; i2<32; i2++){
    int sb = sc*64 + i2*2 + s_off;
    __syncthreads();
    #pragma unroll
    for(int ti=0; ti<4; ti++){
      int row = w*32 + ti*8 + rIn;
      gload16(Q + ((int64_t)sb*LSEQ + q0 + row)*DM + h*DHD + d16*8, &As[(w*32+ti*8)*64]);
      gload16(K + ((int64_t)sb*LSEQ + k0t + row)*DM + h*DHD + d16*8, &Bs[(w*32+ti*8)*64]);
    }
    __syncthreads();
    #pragma unroll
    for(int kk=0;kk<2;kk++){
      int p = (kk*4+quad) ^ (lane&7);
      bf16x8 af[4], bfv[4];
      #pragma unroll
      for(int i=0;i<4;i++) af[i]  = *(const bf16x8*)&As[(mw+i*16+ln15)*64 + p*8];
      #pragma unroll
      for(int j=0;j<4;j++) bfv[j] = *(const bf16x8*)&Bs[(nw+j*16+ln15)*64 + p*8];
      #pragma unroll
      for(int i=0;i<4;i++)
        #pragma unroll
        for(int j=0;j<4;j++)
          acc[i][j] = __builtin_amdgcn_mfma_f32_16x16x32_bf16(af[i], bfv[j], acc[i][j], 0,0,0);
    }
  }
  int64_t slab = (int64_t)sc*NH*LL;
  #pragma unroll
  for(int i=0;i<4;i++)
    #pragma unroll
    for(int reg=0;reg<4;reg++){
      int q = q0 + mw + i*16 + quad*4 + reg;
      float* rp = scores + slab + ((int64_t)h*LSEQ + q)*LSEQ + k0t + nw + ln15;
      #pragma unroll
      for(int j=0;j<4;j++) rp[j*16] = acc[i][j][reg];
    }
}

// ---------------- K8: sum slabs + bias, softmax over k -> P bf16 -----------
__global__ __launch_bounds__(128) void k_softmax(const float* __restrict__ scores,
    const float* __restrict__ bias, u16* __restrict__ Pb){
  int hq = blockIdx.x, t = threadIdx.x;
  int64_t base = (int64_t)hq*LSEQ;
  float v[3];
  #pragma unroll
  for(int i=0;i<3;i++){
    int k = t + i*128;
    float x = bias[base+k];
    x += scores[base+k];
    x += scores[(int64_t)1*NH*LL + base + k];
    x += scores[(int64_t)2*NH*LL + base + k];
    x += scores[(int64_t)3*NH*LL + base + k];
    v[i]=x;
  }
  __shared__ float red[2], red2[2];
  int wv=t>>6, ln=t&63;
  float m = fmaxf(fmaxf(v[0],v[1]),v[2]);
  m = wmax(m);
  if(ln==0) red[wv]=m;
  __syncthreads();
  m = fmaxf(red[0],red[1]);
  float e = __expf(v[0]-m)+__expf(v[1]-m)+__expf(v[2]-m);
  e = wsum(e);
  if(ln==0) red2[wv]=e;
  __syncthreads();
  float inv = 1.f/(red2[0]+red2[1]);
  #pragma unroll
  for(int i=0;i<3;i++) Pb[base + t + i*128] = f2b(__expf(v[i]-m)*inv);
}

// ---------------- K9: PV. C[(s,d)][q] = sum_k VT[h][(s,d)][k] * P[h][q][k] --
__global__ __launch_bounds__(256) void k_pv(const u16* __restrict__ VT,
    const u16* __restrict__ Pb, const u16* __restrict__ gbuf,
    u16* __restrict__ attn){
  __shared__ short As[128*64];
  __shared__ short Bs[128*64];
  int t = threadIdx.x;
  int w = t>>6, lane = t&63, ln15 = lane&15, quad = lane>>4;
  int rIn = lane>>3, cch = lane&7;
  int mw = (w>>1)*64, nw = (w&1)*64;
  int mx = blockIdx.x, ny = blockIdx.y, h = blockIdx.z;
  int g = cch ^ rIn;
  f32x4 acc[4][4] = {};
  for(int it=0; it<6; it++){
    int k0 = it*64;
    __syncthreads();
    #pragma unroll
    for(int ti=0; ti<4; ti++){
      int row = w*32 + ti*8 + rIn;
      gload16(VT + ((int64_t)h*8192 + mx*128 + row)*LSEQ + k0 + g*8, &As[(w*32+ti*8)*64]);
      gload16(Pb + ((int64_t)h*LSEQ + ny*128 + row)*LSEQ + k0 + g*8, &Bs[(w*32+ti*8)*64]);
    }
    __syncthreads();
    #pragma unroll
    for(int kk=0;kk<2;kk++){
      int p = (kk*4+quad) ^ (lane&7);
      bf16x8 af[4], bfv[4];
      #pragma unroll
      for(int i=0;i<4;i++) af[i]  = *(const bf16x8*)&As[(mw+i*16+ln15)*64 + p*8];
      #pragma unroll
      for(int j=0;j<4;j++) bfv[j] = *(const bf16x8*)&Bs[(nw+j*16+ln15)*64 + p*8];
      #pragma unroll
      for(int i=0;i<4;i++)
        #pragma unroll
        for(int j=0;j<4;j++)
          acc[i][j] = __builtin_amdgcn_mfma_f32_16x16x32_bf16(af[i], bfv[j], acc[i][j], 0,0,0);
    }
  }
  #pragma unroll
  for(int i=0;i<4;i++){
    int m0 = mx*128 + mw + i*16 + quad*4;
    int s = m0>>5, d0 = m0&31;
    #pragma unroll
    for(int j=0;j<4;j++){
      int q = ny*128 + nw + j*16 + ln15;
      int64_t base = ((int64_t)s*LSEQ + q)*DM + h*DHD + d0;
      ushort4 gv = *(const ushort4*)(gbuf + base);
      ushort4 o;
      o.x = f2b(acc[i][j][0]*b2f(gv.x));
      o.y = f2b(acc[i][j][1]*b2f(gv.y));
      o.z = f2b(acc[i][j][2]*b2f(gv.z));
      o.w = f2b(acc[i][j][3]*b2f(gv.w));
      *(ushort4*)(attn + base) = o;
    }
  }
}

// ---------------- K10: out = attnout @ wo + bo (fp32 out) ------------------
// Same A-once + reg-B structure as k_projf; both 128-col tiles in one block.
__global__ __launch_bounds__(256) void k_final(const u16* __restrict__ A,
    const u16* __restrict__ WOT, const float* __restrict__ bo,
    float* __restrict__ out){
  __shared__ short As[128*256];        // 64 KB
  int t = threadIdx.x;
  int w = t>>6, lane = t&63, ln15 = lane&15, quad = lane>>4;
  int mw = (w>>1)*64, nw = (w&1)*64;
  int64_t r0 = (int64_t)blockIdx.x*128;

  {
    int rowl = lane>>5;
    int pc = lane&31;
    #pragma unroll
    for(int m=0;m<16;m++){
      int q = w*16+m;
      int row = 2*q + rowl;
      int gch = pc ^ (row&7);
      gload16(A + (r0+row)*DM + gch*8, &As[q*512]);
    }
  }
  __syncthreads();

  for(int nt=0; nt<2; nt++){
    int n0 = nt*128;
    f32x4 acc[4][4] = {};
    #pragma unroll
    for(int ks=0; ks<8; ks++){
      bf16x8 af[4], bfv[4];
      #pragma unroll
      for(int j=0;j<4;j++)
        bfv[j] = *(const bf16x8*)(WOT + (int64_t)(n0+nw+j*16+ln15)*DM + ks*32 + quad*8);
      #pragma unroll
      for(int i=0;i<4;i++){
        int row = mw+i*16+ln15;
        af[i] = *(const bf16x8*)&As[row*256 + (((ks*4+quad) ^ (ln15&7)))*8];
      }
      #pragma unroll
      for(int i=0;i<4;i++)
        #pragma unroll
        for(int j=0;j<4;j++)
          acc[i][j] = __builtin_amdgcn_mfma_f32_16x16x32_bf16(af[i], bfv[j], acc[i][j], 0,0,0);
    }
    float bv[4];
    #pragma unroll
    for(int j=0;j<4;j++) bv[j] = bo[n0 + nw + j*16 + ln15];
    #pragma unroll
    for(int i=0;i<4;i++)
      #pragma unroll
      for(int reg=0;reg<4;reg++){
        int64_t r = r0 + mw + i*16 + quad*4 + reg;
        float* rp = out + r*DM + n0 + nw + ln15;
        #pragma unroll
        for(int j=0;j<4;j++) rp[j*16] = acc[i][j][reg] + bv[j];
      }
  }
}

extern "C" void kernel_launch(void* const* d_in, const int* in_sizes, int n_in,
                              void* d_out, int out_size, void* d_ws, size_t ws_size,
                              hipStream_t stream){
  const float* msa    = (const float*)d_in[0];
  const float* pair   = (const float*)d_in[1];
  const float* lmg    = (const float*)d_in[2];
  const float* lmb    = (const float*)d_in[3];
  const float* lpg    = (const float*)d_in[4];
  const float* lpb    = (const float*)d_in[5];
  const float* sw_q_w = (const float*)d_in[6];
  const float* sw_q_b = (const float*)d_in[7];
  const float* sw_k_w = (const float*)d_in[8];
  // d_in[9] = sw_k_b: constant over n, cancels in softmax over n.
  const float* wq     = (const float*)d_in[10];
  const float* wk     = (const float*)d_in[11];
  const float* wv     = (const float*)d_in[12];
  const float* wb     = (const float*)d_in[13];
  const float* wg     = (const float*)d_in[14];
  const float* bg     = (const float*)d_in[15];
  const float* wo     = (const float*)d_in[16];
  const float* bo     = (const float*)d_in[17];
  float* out = (float*)d_out;

  // workspace layout (~285 MB)
  u16* msa_n = (u16*)d_ws;                       // [NL][256] bf16
  u16* qb    = msa_n + (int64_t)NL*DM;
  u16* kb    = qb + (int64_t)NL*DM;
  u16* gbuf  = kb + (int64_t)NL*DM;
  u16* VT    = gbuf + (int64_t)NL*DM;            // [8][256][32][384] bf16
  u16* Pb    = VT + (int64_t)NL*DM;              // [8][384][384] bf16
  u16* WTall = Pb + (int64_t)NH*LSEQ*LSEQ;       // [1024][256] bf16
  u16* WOT   = WTall + 1024*DM;                  // [256][256] bf16
  float* u_buf = (float*)(WOT + DM*DM);          // [384][8][256] f32
  float* sw  = u_buf + (int64_t)LSEQ*NH*DM;      // [256*384][8] f32
  float* bias = sw + (int64_t)NL*NH;             // [8][384][384] f32
  float* scores = bias + (int64_t)NH*LL;         // 4 slabs [8][384][384] f32
  u16* attnout = msa_n;                          // alias: msa_n dead after proj

  k_ln_msa<<<NL/4, 256, 0, stream>>>(msa, lmg, lmb, msa_n);
  k_wconv<<<dim3(4,4,5), 256, 0, stream>>>(wq, wk, wv, wg, wo, WTall, WOT);
  k_u<<<LSEQ, 256, 0, stream>>>(msa_n, sw_q_w, sw_q_b, sw_k_w, u_buf);
  k_seqw<<<LSEQ, 256, 0, stream>>>(msa_n, u_buf, sw);
  k_bias<<<LL/256, 256, 0, stream>>>(pair, lpg, lpb, wb, bias);
  k_projf<<<dim3(NL/128), 256, 0, stream>>>(msa_n, WTall, qb, kb, gbuf, VT, sw, bg);
  k_scores<<<dim3(3,3,32), 256, 0, stream>>>(qb, kb, scores);
  k_softmax<<<NH*LSEQ, 128, 0, stream>>>(scores, bias, Pb);
  k_pv<<<dim3(64,3,NH), 256, 0, stream>>>(VT, Pb, gbuf, attnout);
  k_final<<<dim3(NL/128), 256, 0, stream>>>(attnout, WOT, bo, out);
}

// Round 4
// 703.109 us; speedup vs baseline: 1.0793x; 1.0553x over previous
//
#include <hip/hip_runtime.h>
#include <hip/hip_fp16.h>
#include <stdint.h>

#define NSEQ 256
#define LSEQ 384
#define DM   256
#define DP   128
#define NH   8
#define DHD  32
#define NL   (NSEQ*LSEQ)   /* 98304 */
#define LL   (LSEQ*LSEQ)   /* 147456 */
#define SCALE 0.17677669529663687f

typedef unsigned short u16;
typedef short bf16x8 __attribute__((ext_vector_type(8)));
typedef float f32x4 __attribute__((ext_vector_type(4)));

__device__ __forceinline__ float b2f(u16 s){
  union { uint32_t u; float f; } v; v.u = ((uint32_t)s)<<16; return v.f;
}
__device__ __forceinline__ u16 f2b(float f){
  union { float f; uint32_t u; } v; v.f = f;
  uint32_t u = v.u;
  return (u16)((u + 0x7FFFu + ((u>>16)&1u)) >> 16);
}
__device__ __forceinline__ float wsum(float x){
  #pragma unroll
  for(int o=32;o>0;o>>=1) x += __shfl_xor(x,o,64);
  return x;
}
__device__ __forceinline__ float wmax(float x){
  #pragma unroll
  for(int o=32;o>0;o>>=1) x = fmaxf(x, __shfl_xor(x,o,64));
  return x;
}
// async 16B global->LDS. LDS dest = wave-uniform base + lane*16.
__device__ __forceinline__ void gload16(const void* g, void* l){
  __builtin_amdgcn_global_load_lds((const __attribute__((address_space(1))) void*)g,
      (__attribute__((address_space(3))) void*)l, 16, 0, 0);
}

// ---------------- K1: LayerNorm(msa) -> bf16, wave per row ----------------
__global__ __launch_bounds__(256) void k_ln_msa(const float* __restrict__ msa,
    const float* __restrict__ g, const float* __restrict__ b, u16* __restrict__ out){
  int lane = threadIdx.x & 63;
  int64_t row = (int64_t)blockIdx.x*4 + (threadIdx.x>>6);
  const float4 x = *(const float4*)(msa + row*DM + lane*4);
  float s = x.x+x.y+x.z+x.w;
  float q = x.x*x.x+x.y*x.y+x.z*x.z+x.w*x.w;
  s = wsum(s); q = wsum(q);
  float mean = s*(1.0f/DM);
  float rstd = rsqrtf(q*(1.0f/DM) - mean*mean + 1e-5f);
  int c = lane*4;
  float4 gv = *(const float4*)(g+c);
  float4 bv = *(const float4*)(b+c);
  ushort4 o;
  o.x=f2b((x.x-mean)*rstd*gv.x+bv.x);
  o.y=f2b((x.y-mean)*rstd*gv.y+bv.y);
  o.z=f2b((x.z-mean)*rstd*gv.z+bv.z);
  o.w=f2b((x.w-mean)*rstd*gv.w+bv.w);
  *(ushort4*)(out + row*DM + c) = o;
}

// ---------------- K2: weight convert+transpose fp32 -> bf16 ----------------
__global__ __launch_bounds__(256) void k_wconv(const float* __restrict__ wq,
    const float* __restrict__ wk, const float* __restrict__ wv,
    const float* __restrict__ wg, const float* __restrict__ wo,
    u16* __restrict__ WTall, u16* __restrict__ WOT){
  __shared__ float tile[64][65];
  int z = blockIdx.z;
  const float* src = (z==0)?wq:(z==1)?wk:(z==2)?wv:(z==3)?wg:wo;
  u16* dst = (z<4) ? (WTall + z*DM*DM) : WOT;
  int k0 = blockIdx.x*64, n0 = blockIdx.y*64, t = threadIdx.x;
  int r = t>>4, c4 = (t&15)*4;
  #pragma unroll
  for(int it=0; it<4; it++){
    float4 v = *(const float4*)(src + (int64_t)(k0 + it*16 + r)*DM + n0 + c4);
    tile[it*16+r][c4+0]=v.x; tile[it*16+r][c4+1]=v.y;
    tile[it*16+r][c4+2]=v.z; tile[it*16+r][c4+3]=v.w;
  }
  __syncthreads();
  #pragma unroll
  for(int it=0; it<4; it++){
    int nl = it*16 + r, kl = c4;
    ushort4 o;
    o.x=f2b(tile[kl+0][nl]); o.y=f2b(tile[kl+1][nl]);
    o.z=f2b(tile[kl+2][nl]); o.w=f2b(tile[kl+3][nl]);
    *(ushort4*)(dst + (int64_t)(n0+nl)*DM + k0 + kl) = o;
  }
}

// ---------------- K3: u[l,h,c] = sum_d sw_k_w[c,h*32+d] * swq[l,h,d] -------
__global__ __launch_bounds__(256) void k_u(const u16* __restrict__ msa_n,
    const float* __restrict__ sw_q_w, const float* __restrict__ sw_q_b,
    const float* __restrict__ sw_k_w, float* __restrict__ u){
  __shared__ float tar[DM];
  __shared__ float swq[DM];
  int l = blockIdx.x, t = threadIdx.x;
  tar[t] = b2f(msa_n[(int64_t)l*DM + t]);
  __syncthreads();
  float acc = sw_q_b[t];
  for(int c=0;c<DM;c++) acc += tar[c]*sw_q_w[c*DM + t];
  swq[t] = acc * SCALE;
  __syncthreads();
  float res[NH];
  #pragma unroll
  for(int h=0;h<NH;h++){
    float a = 0.f;
    #pragma unroll
    for(int d=0;d<DHD;d+=4){
      float4 w = *(const float4*)(sw_k_w + t*DM + h*DHD + d);
      a += w.x*swq[h*DHD+d] + w.y*swq[h*DHD+d+1] + w.z*swq[h*DHD+d+2] + w.w*swq[h*DHD+d+3];
    }
    res[h]=a;
  }
  #pragma unroll
  for(int h=0;h<NH;h++) u[((int64_t)l*NH + h)*DM + t] = res[h];
}

// ---------------- K4: sw_logits + softmax over n -> seq_weight[n,l,h] ------
__global__ __launch_bounds__(256) void k_seqw(const u16* __restrict__ msa_n,
    const float* __restrict__ u, float* __restrict__ sw){
  __shared__ float ul[NH*DM];
  __shared__ float lg[NH*256];
  __shared__ float mx[NH], sm[NH];
  int l = blockIdx.x, t = threadIdx.x;
  #pragma unroll
  for(int h=0;h<NH;h++) ul[h*DM+t] = u[((int64_t)l*NH+h)*DM + t];
  __syncthreads();
  float acc[NH] = {};
  const u16* row = msa_n + ((int64_t)t*LSEQ + l)*DM;   // n = t
  for(int c=0;c<DM;c+=4){
    ushort4 xv = *(const ushort4*)(row + c);
    float x0=b2f(xv.x), x1=b2f(xv.y), x2=b2f(xv.z), x3=b2f(xv.w);
    #pragma unroll
    for(int h=0;h<NH;h++)
      acc[h] += x0*ul[h*DM+c] + x1*ul[h*DM+c+1] + x2*ul[h*DM+c+2] + x3*ul[h*DM+c+3];
  }
  #pragma unroll
  for(int h=0;h<NH;h++) lg[h*256+t] = acc[h];
  __syncthreads();
  int wv = t>>6, ln = t&63;
  for(int h=wv; h<NH; h+=4){
    float a=lg[h*256+ln], b=lg[h*256+ln+64], c=lg[h*256+ln+128], d=lg[h*256+ln+192];
    float m = wmax(fmaxf(fmaxf(a,b),fmaxf(c,d)));
    float e = __expf(a-m)+__expf(b-m)+__expf(c-m)+__expf(d-m);
    e = wsum(e);
    if(ln==0){ mx[h]=m; sm[h]=1.f/e; }
  }
  __syncthreads();
  float o[NH];
  #pragma unroll
  for(int h=0;h<NH;h++) o[h] = __expf(acc[h]-mx[h])*sm[h];
  float* dst = sw + ((int64_t)t*LSEQ + l)*NH;
  *(float4*)dst     = make_float4(o[0],o[1],o[2],o[3]);
  *(float4*)(dst+4) = make_float4(o[4],o[5],o[6],o[7]);
}

// ---------------- K5: bias[h][q][k] = LN(pair[q,k,:]) @ wb -----------------
__global__ __launch_bounds__(256) void k_bias(const float* __restrict__ pair,
    const float* __restrict__ g, const float* __restrict__ b,
    const float* __restrict__ wb, float* __restrict__ bias){
  int64_t row = (int64_t)blockIdx.x*256 + threadIdx.x;   // over L*L
  const float* pr = pair + row*DP;
  uint2 xs[32];                       // 128 channels as packed fp16
  float s = 0.f, q = 0.f;
  #pragma unroll
  for(int i=0;i<32;i++){
    float4 v = *(const float4*)(pr + i*4);
    s += v.x+v.y+v.z+v.w;
    q += v.x*v.x+v.y*v.y+v.z*v.z+v.w*v.w;
    __half2 p0 = __floats2half2_rn(v.x, v.y);
    __half2 p1 = __floats2half2_rn(v.z, v.w);
    xs[i].x = *(const uint32_t*)&p0;
    xs[i].y = *(const uint32_t*)&p1;
  }
  float mean = s*(1.f/DP);
  float rstd = rsqrtf(q*(1.f/DP) - mean*mean + 1e-5f);
  float acc[NH] = {};
  #pragma unroll
  for(int i=0;i<32;i++){
    __half2 p0 = *(const __half2*)&xs[i].x;
    __half2 p1 = *(const __half2*)&xs[i].y;
    float2 f0 = __half22float2(p0);
    float2 f1 = __half22float2(p1);
    float xv[4] = {f0.x, f0.y, f1.x, f1.y};
    #pragma unroll
    for(int c4=0;c4<4;c4++){
      int c = i*4 + c4;
      float y = (xv[c4]-mean)*rstd*g[c] + b[c];
      #pragma unroll
      for(int h=0;h<NH;h++) acc[h] += y*wb[c*NH+h];
    }
  }
  #pragma unroll
  for(int h=0;h<NH;h++) bias[(int64_t)h*LL + row] = acc[h];
}

// ==================== MFMA cores ============================================
// k_projf/k_final: A-strip (128x256 bf16, 64KB) staged ONCE; B col-tile
// (128x256, 64KB) staged ONCE PER COL-TILE into a second LDS buffer shared
// by all 4 waves (B L2 traffic read once per block, batched gload_lds).
// Accumulate loop (8 K-slices) is pure LDS+MFMA, no barriers, no VMEM.
// 128 KB LDS/block. Swizzle: chunk c of row r stored at phys c^(r&7).

// ---------------- K6: fused projection, one block per 128-row strip --------
__global__ __launch_bounds__(256) void k_projf(const u16* __restrict__ A,
    const u16* __restrict__ WT, u16* __restrict__ qb, u16* __restrict__ kb,
    u16* __restrict__ gbuf, u16* __restrict__ VT,
    const float* __restrict__ sw, const float* __restrict__ bg){
  __shared__ short As[128*256];        // 64 KB
  __shared__ short Bs[128*256];        // 64 KB
  int t = threadIdx.x;
  int w = t>>6, lane = t&63, ln15 = lane&15, quad = lane>>4;
  int mw = (w>>1)*64, nw = (w&1)*64;
  int bx = blockIdx.x;                 // 0..767 row strip
  int64_t r0 = (int64_t)bx*128;
  int rowl = lane>>5;                  // 0..1 within the 2-row chunk
  int pc = lane&31;                    // phys 16B chunk within 512B row

  // ---- stage A strip once: 64 gload16 (1KB each = 2 rows), 16 per wave ----
  #pragma unroll
  for(int m=0;m<16;m++){
    int q = w*16+m;
    int row = 2*q + rowl;
    int gch = pc ^ (row&7);            // logical chunk that belongs at phys pc
    gload16(A + (r0+row)*DM + gch*8, &As[q*512]);
  }

  for(int nt=0; nt<8; nt++){
    if(nt>0) __syncthreads();          // all reads of Bs(nt-1) done
    // ---- stage B col-tile nt (shared by all waves) ----
    #pragma unroll
    for(int m=0;m<16;m++){
      int q = w*16+m;
      int row = 2*q + rowl;
      int gch = pc ^ (row&7);
      gload16(WT + (int64_t)(nt*128+row)*DM + gch*8, &Bs[q*512]);
    }
    __syncthreads();                   // As (nt==0) and Bs staged

    f32x4 acc[4][4] = {};
    #pragma unroll
    for(int ks=0; ks<8; ks++){         // K-slice of 32
      int pch = ((ks*4+quad) ^ (ln15&7))*8;
      bf16x8 af[4], bfv[4];
      #pragma unroll
      for(int i=0;i<4;i++) af[i]  = *(const bf16x8*)&As[(mw+i*16+ln15)*256 + pch];
      #pragma unroll
      for(int j=0;j<4;j++) bfv[j] = *(const bf16x8*)&Bs[(nw+j*16+ln15)*256 + pch];
      #pragma unroll
      for(int i=0;i<4;i++)
        #pragma unroll
        for(int j=0;j<4;j++)
          acc[i][j] = __builtin_amdgcn_mfma_f32_16x16x32_bf16(af[i], bfv[j], acc[i][j], 0,0,0);
    }
    // ---- epilogue for this col-tile ----
    int mode = nt>>1;
    int cmb = (nt&1)*128 + nw;
    if(mode==2){
      // V: write transposed VT[h][s][d][kpos], 4 regs = 4 consecutive kpos
      int s = bx/3, kb3 = (bx%3)*128 + mw;
      #pragma unroll
      for(int j=0;j<4;j++){
        int cm = cmb + j*16 + ln15;
        int hh = cm>>5, d = cm&31;
        #pragma unroll
        for(int i=0;i<4;i++){
          int kpos0 = kb3 + i*16 + quad*4;
          ushort4 o;
          o.x=f2b(acc[i][j][0]); o.y=f2b(acc[i][j][1]);
          o.z=f2b(acc[i][j][2]); o.w=f2b(acc[i][j][3]);
          *(ushort4*)(VT + ((int64_t)(hh*NSEQ+s)*DHD + d)*LSEQ + kpos0) = o;
        }
      }
    } else {
      u16* dst = (mode==0)?qb:(mode==1)?kb:gbuf;
      float bgv[4];
      if(mode==3){
        #pragma unroll
        for(int j=0;j<4;j++) bgv[j] = bg[cmb + j*16 + ln15];
      }
      #pragma unroll
      for(int i=0;i<4;i++)
        #pragma unroll
        for(int reg=0;reg<4;reg++){
          int64_t rr = r0 + mw + i*16 + quad*4 + reg;
          #pragma unroll
          for(int j=0;j<4;j++){
            int cm = cmb + j*16 + ln15;
            float v = acc[i][j][reg];
            if(mode==0)      v *= sw[rr*NH + (cm>>5)];
            else if(mode==1) v *= SCALE;
            else             v = 1.f/(1.f+__expf(-(v+bgv[j])));
            dst[rr*DM + cm] = f2b(v);
          }
        }
    }
  }
}

// ---------------- K7: scores slab sc: S[h][q][k] += Q.K over s-chunk -------
__global__ __launch_bounds__(256) void k_scores(const u16* __restrict__ Q,
    const u16* __restrict__ K, float* __restrict__ scores){
  __shared__ short As[128*64];
  __shared__ short Bs[128*64];
  int t = threadIdx.x;
  int w = t>>6, lane = t&63, ln15 = lane&15, quad = lane>>4;
  int rIn = lane>>3, cch = lane&7;
  int mw = (w>>1)*64, nw = (w&1)*64;
  int q0 = blockIdx.x*128, k0t = blockIdx.y*128;
  int h = blockIdx.z>>2, sc = blockIdx.z&3;
  int g = cch ^ rIn;
  int s_off = g>>2, d16 = g&3;
  f32x4 acc[4][4] = {};
  for(int i2=0; i2<32; i2++){
    int sb = sc*64 + i2*2 + s_off;
    __syncthreads();
    #pragma unroll
    for(int ti=0; ti<4; ti++){
      int row = w*32 + ti*8 + rIn;
      gload16(Q + ((int64_t)sb*LSEQ + q0 + row)*DM + h*DHD + d16*8, &As[(w*32+ti*8)*64]);
      gload16(K + ((int64_t)sb*LSEQ + k0t + row)*DM + h*DHD + d16*8, &Bs[(w*32+ti*8)*64]);
    }
    __syncthreads();
    #pragma unroll
    for(int kk=0;kk<2;kk++){
      int p = (kk*4+quad) ^ (lane&7);
      bf16x8 af[4], bfv[4];
      #pragma unroll
      for(int i=0;i<4;i++) af[i]  = *(const bf16x8*)&As[(mw+i*16+ln15)*64 + p*8];
      #pragma unroll
      for(int j=0;j<4;j++) bfv[j] = *(const bf16x8*)&Bs[(nw+j*16+ln15)*64 + p*8];
      #pragma unroll
      for(int i=0;i<4;i++)
        #pragma unroll
        for(int j=0;j<4;j++)
          acc[i][j] = __builtin_amdgcn_mfma_f32_16x16x32_bf16(af[i], bfv[j], acc[i][j], 0,0,0);
    }
  }
  int64_t slab = (int64_t)sc*NH*LL;
  #pragma unroll
  for(int i=0;i<4;i++)
    #pragma unroll
    for(int reg=0;reg<4;reg++){
      int q = q0 + mw + i*16 + quad*4 + reg;
      float* rp = scores + slab + ((int64_t)h*LSEQ + q)*LSEQ + k0t + nw + ln15;
      #pragma unroll
      for(int j=0;j<4;j++) rp[j*16] = acc[i][j][reg];
    }
}

// ---------------- K8: sum slabs + bias, softmax over k -> P bf16 -----------
__global__ __launch_bounds__(128) void k_softmax(const float* __restrict__ scores,
    const float* __restrict__ bias, u16* __restrict__ Pb){
  int hq = blockIdx.x, t = threadIdx.x;
  int64_t base = (int64_t)hq*LSEQ;
  float v[3];
  #pragma unroll
  for(int i=0;i<3;i++){
    int k = t + i*128;
    float x = bias[base+k];
    x += scores[base+k];
    x += scores[(int64_t)1*NH*LL + base + k];
    x += scores[(int64_t)2*NH*LL + base + k];
    x += scores[(int64_t)3*NH*LL + base + k];
    v[i]=x;
  }
  __shared__ float red[2], red2[2];
  int wv=t>>6, ln=t&63;
  float m = fmaxf(fmaxf(v[0],v[1]),v[2]);
  m = wmax(m);
  if(ln==0) red[wv]=m;
  __syncthreads();
  m = fmaxf(red[0],red[1]);
  float e = __expf(v[0]-m)+__expf(v[1]-m)+__expf(v[2]-m);
  e = wsum(e);
  if(ln==0) red2[wv]=e;
  __syncthreads();
  float inv = 1.f/(red2[0]+red2[1]);
  #pragma unroll
  for(int i=0;i<3;i++) Pb[base + t + i*128] = f2b(__expf(v[i]-m)*inv);
}

// ---------------- K9: PV. C[(s,d)][q] = sum_k VT[h][(s,d)][k] * P[h][q][k] --
__global__ __launch_bounds__(256) void k_pv(const u16* __restrict__ VT,
    const u16* __restrict__ Pb, const u16* __restrict__ gbuf,
    u16* __restrict__ attn){
  __shared__ short As[128*64];
  __shared__ short Bs[128*64];
  int t = threadIdx.x;
  int w = t>>6, lane = t&63, ln15 = lane&15, quad = lane>>4;
  int rIn = lane>>3, cch = lane&7;
  int mw = (w>>1)*64, nw = (w&1)*64;
  int mx = blockIdx.x, ny = blockIdx.y, h = blockIdx.z;
  int g = cch ^ rIn;
  f32x4 acc[4][4] = {};
  for(int it=0; it<6; it++){
    int k0 = it*64;
    __syncthreads();
    #pragma unroll
    for(int ti=0; ti<4; ti++){
      int row = w*32 + ti*8 + rIn;
      gload16(VT + ((int64_t)h*8192 + mx*128 + row)*LSEQ + k0 + g*8, &As[(w*32+ti*8)*64]);
      gload16(Pb + ((int64_t)h*LSEQ + ny*128 + row)*LSEQ + k0 + g*8, &Bs[(w*32+ti*8)*64]);
    }
    __syncthreads();
    #pragma unroll
    for(int kk=0;kk<2;kk++){
      int p = (kk*4+quad) ^ (lane&7);
      bf16x8 af[4], bfv[4];
      #pragma unroll
      for(int i=0;i<4;i++) af[i]  = *(const bf16x8*)&As[(mw+i*16+ln15)*64 + p*8];
      #pragma unroll
      for(int j=0;j<4;j++) bfv[j] = *(const bf16x8*)&Bs[(nw+j*16+ln15)*64 + p*8];
      #pragma unroll
      for(int i=0;i<4;i++)
        #pragma unroll
        for(int j=0;j<4;j++)
          acc[i][j] = __builtin_amdgcn_mfma_f32_16x16x32_bf16(af[i], bfv[j], acc[i][j], 0,0,0);
    }
  }
  #pragma unroll
  for(int i=0;i<4;i++){
    int m0 = mx*128 + mw + i*16 + quad*4;
    int s = m0>>5, d0 = m0&31;
    #pragma unroll
    for(int j=0;j<4;j++){
      int q = ny*128 + nw + j*16 + ln15;
      int64_t base = ((int64_t)s*LSEQ + q)*DM + h*DHD + d0;
      ushort4 gv = *(const ushort4*)(gbuf + base);
      ushort4 o;
      o.x = f2b(acc[i][j][0]*b2f(gv.x));
      o.y = f2b(acc[i][j][1]*b2f(gv.y));
      o.z = f2b(acc[i][j][2]*b2f(gv.z));
      o.w = f2b(acc[i][j][3]*b2f(gv.w));
      *(ushort4*)(attn + base) = o;
    }
  }
}

// ---------------- K10: out = attnout @ wo + bo (fp32 out) ------------------
// Same A-once + B-per-col-tile LDS structure as k_projf.
__global__ __launch_bounds__(256) void k_final(const u16* __restrict__ A,
    const u16* __restrict__ WOT, const float* __restrict__ bo,
    float* __restrict__ out){
  __shared__ short As[128*256];        // 64 KB
  __shared__ short Bs[128*256];        // 64 KB
  int t = threadIdx.x;
  int w = t>>6, lane = t&63, ln15 = lane&15, quad = lane>>4;
  int mw = (w>>1)*64, nw = (w&1)*64;
  int64_t r0 = (int64_t)blockIdx.x*128;
  int rowl = lane>>5;
  int pc = lane&31;

  #pragma unroll
  for(int m=0;m<16;m++){
    int q = w*16+m;
    int row = 2*q + rowl;
    int gch = pc ^ (row&7);
    gload16(A + (r0+row)*DM + gch*8, &As[q*512]);
  }

  for(int nt=0; nt<2; nt++){
    if(nt>0) __syncthreads();
    #pragma unroll
    for(int m=0;m<16;m++){
      int q = w*16+m;
      int row = 2*q + rowl;
      int gch = pc ^ (row&7);
      gload16(WOT + (int64_t)(nt*128+row)*DM + gch*8, &Bs[q*512]);
    }
    __syncthreads();

    f32x4 acc[4][4] = {};
    #pragma unroll
    for(int ks=0; ks<8; ks++){
      int pch = ((ks*4+quad) ^ (ln15&7))*8;
      bf16x8 af[4], bfv[4];
      #pragma unroll
      for(int i=0;i<4;i++) af[i]  = *(const bf16x8*)&As[(mw+i*16+ln15)*256 + pch];
      #pragma unroll
      for(int j=0;j<4;j++) bfv[j] = *(const bf16x8*)&Bs[(nw+j*16+ln15)*256 + pch];
      #pragma unroll
      for(int i=0;i<4;i++)
        #pragma unroll
        for(int j=0;j<4;j++)
          acc[i][j] = __builtin_amdgcn_mfma_f32_16x16x32_bf16(af[i], bfv[j], acc[i][j], 0,0,0);
    }
    int n0 = nt*128;
    float bv[4];
    #pragma unroll
    for(int j=0;j<4;j++) bv[j] = bo[n0 + nw + j*16 + ln15];
    #pragma unroll
    for(int i=0;i<4;i++)
      #pragma unroll
      for(int reg=0;reg<4;reg++){
        int64_t r = r0 + mw + i*16 + quad*4 + reg;
        float* rp = out + r*DM + n0 + nw + ln15;
        #pragma unroll
        for(int j=0;j<4;j++) rp[j*16] = acc[i][j][reg] + bv[j];
      }
  }
}

extern "C" void kernel_launch(void* const* d_in, const int* in_sizes, int n_in,
                              void* d_out, int out_size, void* d_ws, size_t ws_size,
                              hipStream_t stream){
  const float* msa    = (const float*)d_in[0];
  const float* pair   = (const float*)d_in[1];
  const float* lmg    = (const float*)d_in[2];
  const float* lmb    = (const float*)d_in[3];
  const float* lpg    = (const float*)d_in[4];
  const float* lpb    = (const float*)d_in[5];
  const float* sw_q_w = (const float*)d_in[6];
  const float* sw_q_b = (const float*)d_in[7];
  const float* sw_k_w = (const float*)d_in[8];
  // d_in[9] = sw_k_b: constant over n, cancels in softmax over n.
  const float* wq     = (const float*)d_in[10];
  const float* wk     = (const float*)d_in[11];
  const float* wv     = (const float*)d_in[12];
  const float* wb     = (const float*)d_in[13];
  const float* wg     = (const float*)d_in[14];
  const float* bg     = (const float*)d_in[15];
  const float* wo     = (const float*)d_in[16];
  const float* bo     = (const float*)d_in[17];
  float* out = (float*)d_out;

  // workspace layout (~285 MB)
  u16* msa_n = (u16*)d_ws;                       // [NL][256] bf16
  u16* qb    = msa_n + (int64_t)NL*DM;
  u16* kb    = qb + (int64_t)NL*DM;
  u16* gbuf  = kb + (int64_t)NL*DM;
  u16* VT    = gbuf + (int64_t)NL*DM;            // [8][256][32][384] bf16
  u16* Pb    = VT + (int64_t)NL*DM;              // [8][384][384] bf16
  u16* WTall = Pb + (int64_t)NH*LSEQ*LSEQ;       // [1024][256] bf16
  u16* WOT   = WTall + 1024*DM;                  // [256][256] bf16
  float* u_buf = (float*)(WOT + DM*DM);          // [384][8][256] f32
  float* sw  = u_buf + (int64_t)LSEQ*NH*DM;      // [256*384][8] f32
  float* bias = sw + (int64_t)NL*NH;             // [8][384][384] f32
  float* scores = bias + (int64_t)NH*LL;         // 4 slabs [8][384][384] f32
  u16* attnout = msa_n;                          // alias: msa_n dead after proj

  k_ln_msa<<<NL/4, 256, 0, stream>>>(msa, lmg, lmb, msa_n);
  k_wconv<<<dim3(4,4,5), 256, 0, stream>>>(wq, wk, wv, wg, wo, WTall, WOT);
  k_u<<<LSEQ, 256, 0, stream>>>(msa_n, sw_q_w, sw_q_b, sw_k_w, u_buf);
  k_seqw<<<LSEQ, 256, 0, stream>>>(msa_n, u_buf, sw);
  k_bias<<<LL/256, 256, 0, stream>>>(pair, lpg, lpb, wb, bias);
  k_projf<<<dim3(NL/128), 256, 0, stream>>>(msa_n, WTall, qb, kb, gbuf, VT, sw, bg);
  k_scores<<<dim3(3,3,32), 256, 0, stream>>>(qb, kb, scores);
  k_softmax<<<NH*LSEQ, 128, 0, stream>>>(scores, bias, Pb);
  k_pv<<<dim3(64,3,NH), 256, 0, stream>>>(VT, Pb, gbuf, attnout);
  k_final<<<dim3(NL/128), 256, 0, stream>>>(attnout, WOT, bo, out);
}

// Round 5
// 682.961 us; speedup vs baseline: 1.1111x; 1.0295x over previous
//
#include <hip/hip_runtime.h>
#include <hip/hip_fp16.h>
#include <stdint.h>

#define NSEQ 256
#define LSEQ 384
#define DM   256
#define DP   128
#define NH   8
#define DHD  32
#define NL   (NSEQ*LSEQ)   /* 98304 */
#define LL   (LSEQ*LSEQ)   /* 147456 */
#define SCALE 0.17677669529663687f

typedef unsigned short u16;
typedef short bf16x8 __attribute__((ext_vector_type(8)));
typedef float f32x4 __attribute__((ext_vector_type(4)));

__device__ __forceinline__ float b2f(u16 s){
  union { uint32_t u; float f; } v; v.u = ((uint32_t)s)<<16; return v.f;
}
__device__ __forceinline__ u16 f2b(float f){
  union { float f; uint32_t u; } v; v.f = f;
  uint32_t u = v.u;
  return (u16)((u + 0x7FFFu + ((u>>16)&1u)) >> 16);
}
__device__ __forceinline__ float wsum(float x){
  #pragma unroll
  for(int o=32;o>0;o>>=1) x += __shfl_xor(x,o,64);
  return x;
}
__device__ __forceinline__ float wmax(float x){
  #pragma unroll
  for(int o=32;o>0;o>>=1) x = fmaxf(x, __shfl_xor(x,o,64));
  return x;
}
// async 16B global->LDS. LDS dest = wave-uniform base + lane*16.
__device__ __forceinline__ void gload16(const void* g, void* l){
  __builtin_amdgcn_global_load_lds((const __attribute__((address_space(1))) void*)g,
      (__attribute__((address_space(3))) void*)l, 16, 0, 0);
}

// ---------------- K1: LayerNorm(msa) -> bf16, wave per row ----------------
__global__ __launch_bounds__(256) void k_ln_msa(const float* __restrict__ msa,
    const float* __restrict__ g, const float* __restrict__ b, u16* __restrict__ out){
  int lane = threadIdx.x & 63;
  int64_t row = (int64_t)blockIdx.x*4 + (threadIdx.x>>6);
  const float4 x = *(const float4*)(msa + row*DM + lane*4);
  float s = x.x+x.y+x.z+x.w;
  float q = x.x*x.x+x.y*x.y+x.z*x.z+x.w*x.w;
  s = wsum(s); q = wsum(q);
  float mean = s*(1.0f/DM);
  float rstd = rsqrtf(q*(1.0f/DM) - mean*mean + 1e-5f);
  int c = lane*4;
  float4 gv = *(const float4*)(g+c);
  float4 bv = *(const float4*)(b+c);
  ushort4 o;
  o.x=f2b((x.x-mean)*rstd*gv.x+bv.x);
  o.y=f2b((x.y-mean)*rstd*gv.y+bv.y);
  o.z=f2b((x.z-mean)*rstd*gv.z+bv.z);
  o.w=f2b((x.w-mean)*rstd*gv.w+bv.w);
  *(ushort4*)(out + row*DM + c) = o;
}

// ---------------- K2: weight convert+transpose fp32 -> bf16 ----------------
__global__ __launch_bounds__(256) void k_wconv(const float* __restrict__ wq,
    const float* __restrict__ wk, const float* __restrict__ wv,
    const float* __restrict__ wg, const float* __restrict__ wo,
    u16* __restrict__ WTall, u16* __restrict__ WOT){
  __shared__ float tile[64][65];
  int z = blockIdx.z;
  const float* src = (z==0)?wq:(z==1)?wk:(z==2)?wv:(z==3)?wg:wo;
  u16* dst = (z<4) ? (WTall + z*DM*DM) : WOT;
  int k0 = blockIdx.x*64, n0 = blockIdx.y*64, t = threadIdx.x;
  int r = t>>4, c4 = (t&15)*4;
  #pragma unroll
  for(int it=0; it<4; it++){
    float4 v = *(const float4*)(src + (int64_t)(k0 + it*16 + r)*DM + n0 + c4);
    tile[it*16+r][c4+0]=v.x; tile[it*16+r][c4+1]=v.y;
    tile[it*16+r][c4+2]=v.z; tile[it*16+r][c4+3]=v.w;
  }
  __syncthreads();
  #pragma unroll
  for(int it=0; it<4; it++){
    int nl = it*16 + r, kl = c4;
    ushort4 o;
    o.x=f2b(tile[kl+0][nl]); o.y=f2b(tile[kl+1][nl]);
    o.z=f2b(tile[kl+2][nl]); o.w=f2b(tile[kl+3][nl]);
    *(ushort4*)(dst + (int64_t)(n0+nl)*DM + k0 + kl) = o;
  }
}

// ---------------- K3: u[l,h,c] = sum_d sw_k_w[c,h*32+d] * swq[l,h,d] -------
__global__ __launch_bounds__(256) void k_u(const u16* __restrict__ msa_n,
    const float* __restrict__ sw_q_w, const float* __restrict__ sw_q_b,
    const float* __restrict__ sw_k_w, float* __restrict__ u){
  __shared__ float tar[DM];
  __shared__ float swq[DM];
  int l = blockIdx.x, t = threadIdx.x;
  tar[t] = b2f(msa_n[(int64_t)l*DM + t]);
  __syncthreads();
  float acc = sw_q_b[t];
  for(int c=0;c<DM;c++) acc += tar[c]*sw_q_w[c*DM + t];
  swq[t] = acc * SCALE;
  __syncthreads();
  float res[NH];
  #pragma unroll
  for(int h=0;h<NH;h++){
    float a = 0.f;
    #pragma unroll
    for(int d=0;d<DHD;d+=4){
      float4 w = *(const float4*)(sw_k_w + t*DM + h*DHD + d);
      a += w.x*swq[h*DHD+d] + w.y*swq[h*DHD+d+1] + w.z*swq[h*DHD+d+2] + w.w*swq[h*DHD+d+3];
    }
    res[h]=a;
  }
  #pragma unroll
  for(int h=0;h<NH;h++) u[((int64_t)l*NH + h)*DM + t] = res[h];
}

// ---------------- K4: sw_logits + softmax over n -> seq_weight[n,l,h] ------
__global__ __launch_bounds__(256) void k_seqw(const u16* __restrict__ msa_n,
    const float* __restrict__ u, float* __restrict__ sw){
  __shared__ float ul[NH*DM];
  __shared__ float lg[NH*256];
  __shared__ float mx[NH], sm[NH];
  int l = blockIdx.x, t = threadIdx.x;
  #pragma unroll
  for(int h=0;h<NH;h++) ul[h*DM+t] = u[((int64_t)l*NH+h)*DM + t];
  __syncthreads();
  float acc[NH] = {};
  const u16* row = msa_n + ((int64_t)t*LSEQ + l)*DM;   // n = t
  for(int c=0;c<DM;c+=4){
    ushort4 xv = *(const ushort4*)(row + c);
    float x0=b2f(xv.x), x1=b2f(xv.y), x2=b2f(xv.z), x3=b2f(xv.w);
    #pragma unroll
    for(int h=0;h<NH;h++)
      acc[h] += x0*ul[h*DM+c] + x1*ul[h*DM+c+1] + x2*ul[h*DM+c+2] + x3*ul[h*DM+c+3];
  }
  #pragma unroll
  for(int h=0;h<NH;h++) lg[h*256+t] = acc[h];
  __syncthreads();
  int wv = t>>6, ln = t&63;
  for(int h=wv; h<NH; h+=4){
    float a=lg[h*256+ln], b=lg[h*256+ln+64], c=lg[h*256+ln+128], d=lg[h*256+ln+192];
    float m = wmax(fmaxf(fmaxf(a,b),fmaxf(c,d)));
    float e = __expf(a-m)+__expf(b-m)+__expf(c-m)+__expf(d-m);
    e = wsum(e);
    if(ln==0){ mx[h]=m; sm[h]=1.f/e; }
  }
  __syncthreads();
  float o[NH];
  #pragma unroll
  for(int h=0;h<NH;h++) o[h] = __expf(acc[h]-mx[h])*sm[h];
  float* dst = sw + ((int64_t)t*LSEQ + l)*NH;
  *(float4*)dst     = make_float4(o[0],o[1],o[2],o[3]);
  *(float4*)(dst+4) = make_float4(o[4],o[5],o[6],o[7]);
}

// ---------------- K5: bias[h][q][k] = LN(pair[q,k,:]) @ wb -----------------
__global__ __launch_bounds__(256) void k_bias(const float* __restrict__ pair,
    const float* __restrict__ g, const float* __restrict__ b,
    const float* __restrict__ wb, float* __restrict__ bias){
  int64_t row = (int64_t)blockIdx.x*256 + threadIdx.x;   // over L*L
  const float* pr = pair + row*DP;
  uint2 xs[32];                       // 128 channels as packed fp16
  float s = 0.f, q = 0.f;
  #pragma unroll
  for(int i=0;i<32;i++){
    float4 v = *(const float4*)(pr + i*4);
    s += v.x+v.y+v.z+v.w;
    q += v.x*v.x+v.y*v.y+v.z*v.z+v.w*v.w;
    __half2 p0 = __floats2half2_rn(v.x, v.y);
    __half2 p1 = __floats2half2_rn(v.z, v.w);
    xs[i].x = *(const uint32_t*)&p0;
    xs[i].y = *(const uint32_t*)&p1;
  }
  float mean = s*(1.f/DP);
  float rstd = rsqrtf(q*(1.f/DP) - mean*mean + 1e-5f);
  float acc[NH] = {};
  #pragma unroll
  for(int i=0;i<32;i++){
    __half2 p0 = *(const __half2*)&xs[i].x;
    __half2 p1 = *(const __half2*)&xs[i].y;
    float2 f0 = __half22float2(p0);
    float2 f1 = __half22float2(p1);
    float xv[4] = {f0.x, f0.y, f1.x, f1.y};
    #pragma unroll
    for(int c4=0;c4<4;c4++){
      int c = i*4 + c4;
      float y = (xv[c4]-mean)*rstd*g[c] + b[c];
      #pragma unroll
      for(int h=0;h<NH;h++) acc[h] += y*wb[c*NH+h];
    }
  }
  #pragma unroll
  for(int h=0;h<NH;h++) bias[(int64_t)h*LL + row] = acc[h];
}

// ==================== MFMA cores ============================================
// v5 k_projf/k_final: 64 KB LDS total -> 2 blocks/CU resident (cross-block
// overlap hides stage/drain latency; the 128KB variant ran 1 block/CU with
// every drain exposed). Tile M=64 (A-strip 32 KB staged once), N=128 col-tile,
// B staged in two 32 KB K-halves. MFMA operands SWAPPED (mfma(B,A)) so each
// lane's f32x4 = 4 consecutive C columns -> ushort4/float4 epilogue stores
// (8 wide stores vs 64 scalar). Swizzle: chunk c of row r at phys c^(r&7).

// ---------------- K6: fused projection, one block per 64-row strip ---------
__global__ __launch_bounds__(256,2) void k_projf(const u16* __restrict__ A,
    const u16* __restrict__ WT, u16* __restrict__ qb, u16* __restrict__ kb,
    u16* __restrict__ gbuf, u16* __restrict__ VT,
    const float* __restrict__ sw, const float* __restrict__ bg){
  __shared__ short As[64*256];         // 32 KB
  __shared__ short Bs[128*128];        // 32 KB (one K-half of col-tile)
  int t = threadIdx.x;
  int w = t>>6, lane = t&63, ln15 = lane&15, quad = lane>>4;
  int mw = (w>>1)*32, nw = (w&1)*64;
  int bx = blockIdx.x;                 // 0..1535 row strip
  int64_t r0 = (int64_t)bx*64;

  // ---- stage A strip once: 64 rows x 512B = 32 gload16, 8 per wave -------
  {
    int rowl = lane>>5;                // 2 rows per 1KB instr
    int pc = lane&31;                  // phys 16B chunk in 512B row
    #pragma unroll
    for(int m=0;m<8;m++){
      int q = w*8+m;                   // two-row unit 0..31
      int row = 2*q + rowl;
      int gch = pc ^ (row&7);
      gload16(A + (r0+row)*DM + gch*8, &As[q*512]);
    }
  }

  for(int nt=0; nt<8; nt++){
    f32x4 acc[4][2] = {};              // [j][i], SWAPPED: regs = 4 consecutive cols
    #pragma unroll
    for(int kh=0; kh<2; kh++){
      __syncthreads();                 // prev Bs reads done (first: trivial)
      // stage B K-half: 128 rows x 256B = 32 gload16, 8/wave, 4 rows/instr
      {
        int rowl4 = lane>>4;           // 0..3
        int pc16 = lane&15;            // phys 16B chunk in 256B row
        #pragma unroll
        for(int m=0;m<8;m++){
          int q = w*8+m;               // four-row unit 0..31
          int row = q*4 + rowl4;
          int gch = pc16 ^ (row&7);
          gload16(WT + (int64_t)(nt*128+row)*DM + kh*128 + gch*8, &Bs[q*512]);
        }
      }
      __syncthreads();                 // staged (also drains A at first pass)
      #pragma unroll
      for(int ks2=0; ks2<4; ks2++){
        bf16x8 af[2], bfv[4];
        #pragma unroll
        for(int i=0;i<2;i++){
          int rw = mw+i*16+ln15;
          int ca = (kh*16 + ks2*4 + quad) ^ (rw&7);
          af[i] = *(const bf16x8*)&As[rw*256 + ca*8];
        }
        #pragma unroll
        for(int j=0;j<4;j++){
          int rw = nw+j*16+ln15;
          int cb = (ks2*4+quad) ^ (rw&7);
          bfv[j] = *(const bf16x8*)&Bs[rw*128 + cb*8];
        }
        #pragma unroll
        for(int j=0;j<4;j++)
          #pragma unroll
          for(int i=0;i<2;i++)
            acc[j][i] = __builtin_amdgcn_mfma_f32_16x16x32_bf16(bfv[j], af[i], acc[j][i], 0,0,0);
      }
    }
    // ---- epilogue: lane holds rows r0+mw+i*16+ln15, cols cmb+j*16+quad*4+reg
    int mode = nt>>1;
    int cmb = (nt&1)*128 + nw;
    if(mode==2){
      // V: VT[h][s][d][kpos]; kpos is per-lane (ln15) -> scalar stores
      int s = bx/6, kpb = (bx%6)*64 + mw;
      #pragma unroll
      for(int j=0;j<4;j++)
        #pragma unroll
        for(int i=0;i<2;i++){
          int kpos = kpb + i*16 + ln15;
          #pragma unroll
          for(int reg=0;reg<4;reg++){
            int cm = cmb + j*16 + quad*4 + reg;
            int hh = cm>>5, d = cm&31;
            VT[((int64_t)(hh*NSEQ+s)*DHD + d)*LSEQ + kpos] = f2b(acc[j][i][reg]);
          }
        }
    } else {
      u16* dst = (mode==0)?qb:(mode==1)?kb:gbuf;
      #pragma unroll
      for(int i=0;i<2;i++){
        int64_t rr = r0 + mw + i*16 + ln15;
        #pragma unroll
        for(int j=0;j<4;j++){
          int cm0 = cmb + j*16 + quad*4;
          ushort4 o;
          #pragma unroll
          for(int reg=0;reg<4;reg++){
            float v = acc[j][i][reg];
            if(mode==0)      v *= sw[rr*NH + ((cm0+reg)>>5)];
            else if(mode==1) v *= SCALE;
            else             v = 1.f/(1.f+__expf(-(v+bg[cm0+reg])));
            ((u16*)&o)[reg] = f2b(v);
          }
          *(ushort4*)(dst + rr*DM + cm0) = o;
        }
      }
    }
  }
}

// ---------------- K7: scores slab sc: S[h][q][k] += Q.K over s-chunk -------
__global__ __launch_bounds__(256) void k_scores(const u16* __restrict__ Q,
    const u16* __restrict__ K, float* __restrict__ scores){
  __shared__ short As[128*64];
  __shared__ short Bs[128*64];
  int t = threadIdx.x;
  int w = t>>6, lane = t&63, ln15 = lane&15, quad = lane>>4;
  int rIn = lane>>3, cch = lane&7;
  int mw = (w>>1)*64, nw = (w&1)*64;
  int q0 = blockIdx.x*128, k0t = blockIdx.y*128;
  int h = blockIdx.z>>2, sc = blockIdx.z&3;
  int g = cch ^ rIn;
  int s_off = g>>2, d16 = g&3;
  f32x4 acc[4][4] = {};
  for(int i2=0; i2<32; i2++){
    int sb = sc*64 + i2*2 + s_off;
    __syncthreads();
    #pragma unroll
    for(int ti=0; ti<4; ti++){
      int row = w*32 + ti*8 + rIn;
      gload16(Q + ((int64_t)sb*LSEQ + q0 + row)*DM + h*DHD + d16*8, &As[(w*32+ti*8)*64]);
      gload16(K + ((int64_t)sb*LSEQ + k0t + row)*DM + h*DHD + d16*8, &Bs[(w*32+ti*8)*64]);
    }
    __syncthreads();
    #pragma unroll
    for(int kk=0;kk<2;kk++){
      int p = (kk*4+quad) ^ (lane&7);
      bf16x8 af[4], bfv[4];
      #pragma unroll
      for(int i=0;i<4;i++) af[i]  = *(const bf16x8*)&As[(mw+i*16+ln15)*64 + p*8];
      #pragma unroll
      for(int j=0;j<4;j++) bfv[j] = *(const bf16x8*)&Bs[(nw+j*16+ln15)*64 + p*8];
      #pragma unroll
      for(int i=0;i<4;i++)
        #pragma unroll
        for(int j=0;j<4;j++)
          acc[i][j] = __builtin_amdgcn_mfma_f32_16x16x32_bf16(af[i], bfv[j], acc[i][j], 0,0,0);
    }
  }
  int64_t slab = (int64_t)sc*NH*LL;
  #pragma unroll
  for(int i=0;i<4;i++)
    #pragma unroll
    for(int reg=0;reg<4;reg++){
      int q = q0 + mw + i*16 + quad*4 + reg;
      float* rp = scores + slab + ((int64_t)h*LSEQ + q)*LSEQ + k0t + nw + ln15;
      #pragma unroll
      for(int j=0;j<4;j++) rp[j*16] = acc[i][j][reg];
    }
}

// ---------------- K8: sum slabs + bias, softmax over k -> P bf16 -----------
__global__ __launch_bounds__(128) void k_softmax(const float* __restrict__ scores,
    const float* __restrict__ bias, u16* __restrict__ Pb){
  int hq = blockIdx.x, t = threadIdx.x;
  int64_t base = (int64_t)hq*LSEQ;
  float v[3];
  #pragma unroll
  for(int i=0;i<3;i++){
    int k = t + i*128;
    float x = bias[base+k];
    x += scores[base+k];
    x += scores[(int64_t)1*NH*LL + base + k];
    x += scores[(int64_t)2*NH*LL + base + k];
    x += scores[(int64_t)3*NH*LL + base + k];
    v[i]=x;
  }
  __shared__ float red[2], red2[2];
  int wv=t>>6, ln=t&63;
  float m = fmaxf(fmaxf(v[0],v[1]),v[2]);
  m = wmax(m);
  if(ln==0) red[wv]=m;
  __syncthreads();
  m = fmaxf(red[0],red[1]);
  float e = __expf(v[0]-m)+__expf(v[1]-m)+__expf(v[2]-m);
  e = wsum(e);
  if(ln==0) red2[wv]=e;
  __syncthreads();
  float inv = 1.f/(red2[0]+red2[1]);
  #pragma unroll
  for(int i=0;i<3;i++) Pb[base + t + i*128] = f2b(__expf(v[i]-m)*inv);
}

// ---------------- K9: PV. C[(s,d)][q] = sum_k VT[h][(s,d)][k] * P[h][q][k] --
__global__ __launch_bounds__(256) void k_pv(const u16* __restrict__ VT,
    const u16* __restrict__ Pb, const u16* __restrict__ gbuf,
    u16* __restrict__ attn){
  __shared__ short As[128*64];
  __shared__ short Bs[128*64];
  int t = threadIdx.x;
  int w = t>>6, lane = t&63, ln15 = lane&15, quad = lane>>4;
  int rIn = lane>>3, cch = lane&7;
  int mw = (w>>1)*64, nw = (w&1)*64;
  int mx = blockIdx.x, ny = blockIdx.y, h = blockIdx.z;
  int g = cch ^ rIn;
  f32x4 acc[4][4] = {};
  for(int it=0; it<6; it++){
    int k0 = it*64;
    __syncthreads();
    #pragma unroll
    for(int ti=0; ti<4; ti++){
      int row = w*32 + ti*8 + rIn;
      gload16(VT + ((int64_t)h*8192 + mx*128 + row)*LSEQ + k0 + g*8, &As[(w*32+ti*8)*64]);
      gload16(Pb + ((int64_t)h*LSEQ + ny*128 + row)*LSEQ + k0 + g*8, &Bs[(w*32+ti*8)*64]);
    }
    __syncthreads();
    #pragma unroll
    for(int kk=0;kk<2;kk++){
      int p = (kk*4+quad) ^ (lane&7);
      bf16x8 af[4], bfv[4];
      #pragma unroll
      for(int i=0;i<4;i++) af[i]  = *(const bf16x8*)&As[(mw+i*16+ln15)*64 + p*8];
      #pragma unroll
      for(int j=0;j<4;j++) bfv[j] = *(const bf16x8*)&Bs[(nw+j*16+ln15)*64 + p*8];
      #pragma unroll
      for(int i=0;i<4;i++)
        #pragma unroll
        for(int j=0;j<4;j++)
          acc[i][j] = __builtin_amdgcn_mfma_f32_16x16x32_bf16(af[i], bfv[j], acc[i][j], 0,0,0);
    }
  }
  #pragma unroll
  for(int i=0;i<4;i++){
    int m0 = mx*128 + mw + i*16 + quad*4;
    int s = m0>>5, d0 = m0&31;
    #pragma unroll
    for(int j=0;j<4;j++){
      int q = ny*128 + nw + j*16 + ln15;
      int64_t base = ((int64_t)s*LSEQ + q)*DM + h*DHD + d0;
      ushort4 gv = *(const ushort4*)(gbuf + base);
      ushort4 o;
      o.x = f2b(acc[i][j][0]*b2f(gv.x));
      o.y = f2b(acc[i][j][1]*b2f(gv.y));
      o.z = f2b(acc[i][j][2]*b2f(gv.z));
      o.w = f2b(acc[i][j][3]*b2f(gv.w));
      *(ushort4*)(attn + base) = o;
    }
  }
}

// ---------------- K10: out = attnout @ wo + bo (fp32 out) ------------------
// Same 64KB/2-block structure as k_projf; swapped epilogue -> float4 stores.
__global__ __launch_bounds__(256,2) void k_final(const u16* __restrict__ A,
    const u16* __restrict__ WOT, const float* __restrict__ bo,
    float* __restrict__ out){
  __shared__ short As[64*256];         // 32 KB
  __shared__ short Bs[128*128];        // 32 KB
  int t = threadIdx.x;
  int w = t>>6, lane = t&63, ln15 = lane&15, quad = lane>>4;
  int mw = (w>>1)*32, nw = (w&1)*64;
  int64_t r0 = (int64_t)blockIdx.x*64;

  {
    int rowl = lane>>5;
    int pc = lane&31;
    #pragma unroll
    for(int m=0;m<8;m++){
      int q = w*8+m;
      int row = 2*q + rowl;
      int gch = pc ^ (row&7);
      gload16(A + (r0+row)*DM + gch*8, &As[q*512]);
    }
  }

  for(int nt=0; nt<2; nt++){
    f32x4 acc[4][2] = {};
    #pragma unroll
    for(int kh=0; kh<2; kh++){
      __syncthreads();
      {
        int rowl4 = lane>>4;
        int pc16 = lane&15;
        #pragma unroll
        for(int m=0;m<8;m++){
          int q = w*8+m;
          int row = q*4 + rowl4;
          int gch = pc16 ^ (row&7);
          gload16(WOT + (int64_t)(nt*128+row)*DM + kh*128 + gch*8, &Bs[q*512]);
        }
      }
      __syncthreads();
      #pragma unroll
      for(int ks2=0; ks2<4; ks2++){
        bf16x8 af[2], bfv[4];
        #pragma unroll
        for(int i=0;i<2;i++){
          int rw = mw+i*16+ln15;
          int ca = (kh*16 + ks2*4 + quad) ^ (rw&7);
          af[i] = *(const bf16x8*)&As[rw*256 + ca*8];
        }
        #pragma unroll
        for(int j=0;j<4;j++){
          int rw = nw+j*16+ln15;
          int cb = (ks2*4+quad) ^ (rw&7);
          bfv[j] = *(const bf16x8*)&Bs[rw*128 + cb*8];
        }
        #pragma unroll
        for(int j=0;j<4;j++)
          #pragma unroll
          for(int i=0;i<2;i++)
            acc[j][i] = __builtin_amdgcn_mfma_f32_16x16x32_bf16(bfv[j], af[i], acc[j][i], 0,0,0);
      }
    }
    int n0 = nt*128;
    #pragma unroll
    for(int i=0;i<2;i++){
      int64_t rr = r0 + mw + i*16 + ln15;
      #pragma unroll
      for(int j=0;j<4;j++){
        int cm0 = n0 + nw + j*16 + quad*4;
        float4 o;
        o.x = acc[j][i][0] + bo[cm0+0];
        o.y = acc[j][i][1] + bo[cm0+1];
        o.z = acc[j][i][2] + bo[cm0+2];
        o.w = acc[j][i][3] + bo[cm0+3];
        *(float4*)(out + rr*DM + cm0) = o;
      }
    }
  }
}

extern "C" void kernel_launch(void* const* d_in, const int* in_sizes, int n_in,
                              void* d_out, int out_size, void* d_ws, size_t ws_size,
                              hipStream_t stream){
  const float* msa    = (const float*)d_in[0];
  const float* pair   = (const float*)d_in[1];
  const float* lmg    = (const float*)d_in[2];
  const float* lmb    = (const float*)d_in[3];
  const float* lpg    = (const float*)d_in[4];
  const float* lpb    = (const float*)d_in[5];
  const float* sw_q_w = (const float*)d_in[6];
  const float* sw_q_b = (const float*)d_in[7];
  const float* sw_k_w = (const float*)d_in[8];
  // d_in[9] = sw_k_b: constant over n, cancels in softmax over n.
  const float* wq     = (const float*)d_in[10];
  const float* wk     = (const float*)d_in[11];
  const float* wv     = (const float*)d_in[12];
  const float* wb     = (const float*)d_in[13];
  const float* wg     = (const float*)d_in[14];
  const float* bg     = (const float*)d_in[15];
  const float* wo     = (const float*)d_in[16];
  const float* bo     = (const float*)d_in[17];
  float* out = (float*)d_out;

  // workspace layout (~285 MB)
  u16* msa_n = (u16*)d_ws;                       // [NL][256] bf16
  u16* qb    = msa_n + (int64_t)NL*DM;
  u16* kb    = qb + (int64_t)NL*DM;
  u16* gbuf  = kb + (int64_t)NL*DM;
  u16* VT    = gbuf + (int64_t)NL*DM;            // [8][256][32][384] bf16
  u16* Pb    = VT + (int64_t)NL*DM;              // [8][384][384] bf16
  u16* WTall = Pb + (int64_t)NH*LSEQ*LSEQ;       // [1024][256] bf16
  u16* WOT   = WTall + 1024*DM;                  // [256][256] bf16
  float* u_buf = (float*)(WOT + DM*DM);          // [384][8][256] f32
  float* sw  = u_buf + (int64_t)LSEQ*NH*DM;      // [256*384][8] f32
  float* bias = sw + (int64_t)NL*NH;             // [8][384][384] f32
  float* scores = bias + (int64_t)NH*LL;         // 4 slabs [8][384][384] f32
  u16* attnout = msa_n;                          // alias: msa_n dead after proj

  k_ln_msa<<<NL/4, 256, 0, stream>>>(msa, lmg, lmb, msa_n);
  k_wconv<<<dim3(4,4,5), 256, 0, stream>>>(wq, wk, wv, wg, wo, WTall, WOT);
  k_u<<<LSEQ, 256, 0, stream>>>(msa_n, sw_q_w, sw_q_b, sw_k_w, u_buf);
  k_seqw<<<LSEQ, 256, 0, stream>>>(msa_n, u_buf, sw);
  k_bias<<<LL/256, 256, 0, stream>>>(pair, lpg, lpb, wb, bias);
  k_projf<<<dim3(NL/64), 256, 0, stream>>>(msa_n, WTall, qb, kb, gbuf, VT, sw, bg);
  k_scores<<<dim3(3,3,32), 256, 0, stream>>>(qb, kb, scores);
  k_softmax<<<NH*LSEQ, 128, 0, stream>>>(scores, bias, Pb);
  k_pv<<<dim3(64,3,NH), 256, 0, stream>>>(VT, Pb, gbuf, attnout);
  k_final<<<dim3(NL/64), 256, 0, stream>>>(attnout, WOT, bo, out);
}

// Round 7
// 662.371 us; speedup vs baseline: 1.1456x; 1.0311x over previous
//
#include <hip/hip_runtime.h>
#include <hip/hip_fp16.h>
#include <stdint.h>

#define NSEQ 256
#define LSEQ 384
#define DM   256
#define DP   128
#define NH   8
#define DHD  32
#define NL   (NSEQ*LSEQ)   /* 98304 */
#define LL   (LSEQ*LSEQ)   /* 147456 */
#define SCALE 0.17677669529663687f

typedef unsigned short u16;
typedef short bf16x8 __attribute__((ext_vector_type(8)));
typedef float f32x4 __attribute__((ext_vector_type(4)));

__device__ __forceinline__ float b2f(u16 s){
  union { uint32_t u; float f; } v; v.u = ((uint32_t)s)<<16; return v.f;
}
__device__ __forceinline__ u16 f2b(float f){
  union { float f; uint32_t u; } v; v.f = f;
  uint32_t u = v.u;
  return (u16)((u + 0x7FFFu + ((u>>16)&1u)) >> 16);
}
__device__ __forceinline__ uint2 pack4(float a,float b,float c,float d){
  uint2 r;
  r.x = (uint32_t)f2b(a) | ((uint32_t)f2b(b)<<16);
  r.y = (uint32_t)f2b(c) | ((uint32_t)f2b(d)<<16);
  return r;
}
__device__ __forceinline__ float wsum(float x){
  #pragma unroll
  for(int o=32;o>0;o>>=1) x += __shfl_xor(x,o,64);
  return x;
}
__device__ __forceinline__ float wmax(float x){
  #pragma unroll
  for(int o=32;o>0;o>>=1) x = fmaxf(x, __shfl_xor(x,o,64));
  return x;
}
// async 16B global->LDS. LDS dest = wave-uniform base + lane*16.
__device__ __forceinline__ void gload16(const void* g, void* l){
  __builtin_amdgcn_global_load_lds((const __attribute__((address_space(1))) void*)g,
      (__attribute__((address_space(3))) void*)l, 16, 0, 0);
}

// ---------------- K1: LayerNorm(msa) -> bf16, wave per row ----------------
__global__ __launch_bounds__(256) void k_ln_msa(const float* __restrict__ msa,
    const float* __restrict__ g, const float* __restrict__ b, u16* __restrict__ out){
  int lane = threadIdx.x & 63;
  int64_t row = (int64_t)blockIdx.x*4 + (threadIdx.x>>6);
  const float4 x = *(const float4*)(msa + row*DM + lane*4);
  float s = x.x+x.y+x.z+x.w;
  float q = x.x*x.x+x.y*x.y+x.z*x.z+x.w*x.w;
  s = wsum(s); q = wsum(q);
  float mean = s*(1.0f/DM);
  float rstd = rsqrtf(q*(1.0f/DM) - mean*mean + 1e-5f);
  int c = lane*4;
  float4 gv = *(const float4*)(g+c);
  float4 bv = *(const float4*)(b+c);
  ushort4 o;
  o.x=f2b((x.x-mean)*rstd*gv.x+bv.x);
  o.y=f2b((x.y-mean)*rstd*gv.y+bv.y);
  o.z=f2b((x.z-mean)*rstd*gv.z+bv.z);
  o.w=f2b((x.w-mean)*rstd*gv.w+bv.w);
  *(ushort4*)(out + row*DM + c) = o;
}

// ---------------- K2: weight convert+transpose fp32 -> bf16 ----------------
__global__ __launch_bounds__(256) void k_wconv(const float* __restrict__ wq,
    const float* __restrict__ wk, const float* __restrict__ wv,
    const float* __restrict__ wg, const float* __restrict__ wo,
    u16* __restrict__ WTall, u16* __restrict__ WOT){
  __shared__ float tile[64][65];
  int z = blockIdx.z;
  const float* src = (z==0)?wq:(z==1)?wk:(z==2)?wv:(z==3)?wg:wo;
  u16* dst = (z<4) ? (WTall + z*DM*DM) : WOT;
  int k0 = blockIdx.x*64, n0 = blockIdx.y*64, t = threadIdx.x;
  int r = t>>4, c4 = (t&15)*4;
  #pragma unroll
  for(int it=0; it<4; it++){
    float4 v = *(const float4*)(src + (int64_t)(k0 + it*16 + r)*DM + n0 + c4);
    tile[it*16+r][c4+0]=v.x; tile[it*16+r][c4+1]=v.y;
    tile[it*16+r][c4+2]=v.z; tile[it*16+r][c4+3]=v.w;
  }
  __syncthreads();
  #pragma unroll
  for(int it=0; it<4; it++){
    int nl = it*16 + r, kl = c4;
    ushort4 o;
    o.x=f2b(tile[kl+0][nl]); o.y=f2b(tile[kl+1][nl]);
    o.z=f2b(tile[kl+2][nl]); o.w=f2b(tile[kl+3][nl]);
    *(ushort4*)(dst + (int64_t)(n0+nl)*DM + k0 + kl) = o;
  }
}

// ---------------- K3: u[l,h,c] = sum_d sw_k_w[c,h*32+d] * swq[l,h,d] -------
__global__ __launch_bounds__(256) void k_u(const u16* __restrict__ msa_n,
    const float* __restrict__ sw_q_w, const float* __restrict__ sw_q_b,
    const float* __restrict__ sw_k_w, float* __restrict__ u){
  __shared__ float tar[DM];
  __shared__ float swq[DM];
  int l = blockIdx.x, t = threadIdx.x;
  tar[t] = b2f(msa_n[(int64_t)l*DM + t]);
  __syncthreads();
  float acc = sw_q_b[t];
  for(int c=0;c<DM;c++) acc += tar[c]*sw_q_w[c*DM + t];
  swq[t] = acc * SCALE;
  __syncthreads();
  float res[NH];
  #pragma unroll
  for(int h=0;h<NH;h++){
    float a = 0.f;
    #pragma unroll
    for(int d=0;d<DHD;d+=4){
      float4 w = *(const float4*)(sw_k_w + t*DM + h*DHD + d);
      a += w.x*swq[h*DHD+d] + w.y*swq[h*DHD+d+1] + w.z*swq[h*DHD+d+2] + w.w*swq[h*DHD+d+3];
    }
    res[h]=a;
  }
  #pragma unroll
  for(int h=0;h<NH;h++) u[((int64_t)l*NH + h)*DM + t] = res[h];
}

// ---------------- K4: sw_logits + softmax over n -> seq_weight[n,l,h] ------
__global__ __launch_bounds__(256) void k_seqw(const u16* __restrict__ msa_n,
    const float* __restrict__ u, float* __restrict__ sw){
  __shared__ float ul[NH*DM];
  __shared__ float lg[NH*256];
  __shared__ float mx[NH], sm[NH];
  int l = blockIdx.x, t = threadIdx.x;
  #pragma unroll
  for(int h=0;h<NH;h++) ul[h*DM+t] = u[((int64_t)l*NH+h)*DM + t];
  __syncthreads();
  float acc[NH] = {};
  const u16* row = msa_n + ((int64_t)t*LSEQ + l)*DM;   // n = t
  for(int c=0;c<DM;c+=4){
    ushort4 xv = *(const ushort4*)(row + c);
    float x0=b2f(xv.x), x1=b2f(xv.y), x2=b2f(xv.z), x3=b2f(xv.w);
    #pragma unroll
    for(int h=0;h<NH;h++)
      acc[h] += x0*ul[h*DM+c] + x1*ul[h*DM+c+1] + x2*ul[h*DM+c+2] + x3*ul[h*DM+c+3];
  }
  #pragma unroll
  for(int h=0;h<NH;h++) lg[h*256+t] = acc[h];
  __syncthreads();
  int wv = t>>6, ln = t&63;
  for(int h=wv; h<NH; h+=4){
    float a=lg[h*256+ln], b=lg[h*256+ln+64], c=lg[h*256+ln+128], d=lg[h*256+ln+192];
    float m = wmax(fmaxf(fmaxf(a,b),fmaxf(c,d)));
    float e = __expf(a-m)+__expf(b-m)+__expf(c-m)+__expf(d-m);
    e = wsum(e);
    if(ln==0){ mx[h]=m; sm[h]=1.f/e; }
  }
  __syncthreads();
  float o[NH];
  #pragma unroll
  for(int h=0;h<NH;h++) o[h] = __expf(acc[h]-mx[h])*sm[h];
  float* dst = sw + ((int64_t)t*LSEQ + l)*NH;
  *(float4*)dst     = make_float4(o[0],o[1],o[2],o[3]);
  *(float4*)(dst+4) = make_float4(o[4],o[5],o[6],o[7]);
}

// ---------------- K5: bias[h][q][k] = LN(pair[q,k,:]) @ wb -----------------
__global__ __launch_bounds__(256) void k_bias(const float* __restrict__ pair,
    const float* __restrict__ g, const float* __restrict__ b,
    const float* __restrict__ wb, float* __restrict__ bias){
  int64_t row = (int64_t)blockIdx.x*256 + threadIdx.x;   // over L*L
  const float* pr = pair + row*DP;
  uint2 xs[32];                       // 128 channels as packed fp16
  float s = 0.f, q = 0.f;
  #pragma unroll
  for(int i=0;i<32;i++){
    float4 v = *(const float4*)(pr + i*4);
    s += v.x+v.y+v.z+v.w;
    q += v.x*v.x+v.y*v.y+v.z*v.z+v.w*v.w;
    __half2 p0 = __floats2half2_rn(v.x, v.y);
    __half2 p1 = __floats2half2_rn(v.z, v.w);
    xs[i].x = *(const uint32_t*)&p0;
    xs[i].y = *(const uint32_t*)&p1;
  }
  float mean = s*(1.f/DP);
  float rstd = rsqrtf(q*(1.f/DP) - mean*mean + 1e-5f);
  float acc[NH] = {};
  #pragma unroll
  for(int i=0;i<32;i++){
    __half2 p0 = *(const __half2*)&xs[i].x;
    __half2 p1 = *(const __half2*)&xs[i].y;
    float2 f0 = __half22float2(p0);
    float2 f1 = __half22float2(p1);
    float xv[4] = {f0.x, f0.y, f1.x, f1.y};
    #pragma unroll
    for(int c4=0;c4<4;c4++){
      int c = i*4 + c4;
      float y = (xv[c4]-mean)*rstd*g[c] + b[c];
      #pragma unroll
      for(int h=0;h<NH;h++) acc[h] += y*wb[c*NH+h];
    }
  }
  #pragma unroll
  for(int h=0;h<NH;h++) bias[(int64_t)h*LL + row] = acc[h];
}

// ==================== MFMA cores ============================================
// v6: T3 prefetch + store-free barriers. k_projf/k_final: As 32 KB staged
// once; Bs double-buffered 2x16 KB (BK=64); STAGE(r+1) issued before compute
// so loads fly under MFMA; ONE barrier/round, drains LOADS ONLY — all
// epilogue results are post-processed+packed into registers and flushed
// outside the barrier path (Q/K once at r=15, V/G after the last barrier).
// 64 KB LDS -> 2 blocks/CU. Swizzle: chunk c of row r at phys c^(r&7).

// ---------------- K6: fused projection, one block per 64-row strip ---------
__global__ __launch_bounds__(256,2) void k_projf(const u16* __restrict__ A,
    const u16* __restrict__ WT, u16* __restrict__ qb, u16* __restrict__ kb,
    u16* __restrict__ gbuf, u16* __restrict__ VT,
    const float* __restrict__ sw, const float* __restrict__ bg){
  __shared__ short As[64*256];        // 32 KB
  __shared__ short Bs[2][128*64];     // 2 x 16 KB
  int t = threadIdx.x;
  int w = t>>6, lane = t&63, ln15 = lane&15, quad = lane>>4;
  int mw = (w>>1)*32, nw = (w&1)*64;
  int bx = blockIdx.x;                // 0..1535 row strip
  int64_t r0 = (int64_t)bx*64;
  int rIn = lane>>3, cch = lane&7;
  int gB = cch ^ rIn;                 // B-stage swizzled chunk (row&7==rIn)

  // ---- stage A strip once: 64 rows x 512B ----
  {
    int rowl = lane>>5, pc = lane&31;
    #pragma unroll
    for(int m=0;m<8;m++){
      int q = w*8+m;
      int row = 2*q + rowl;
      int gch = pc ^ (row&7);
      gload16(A + (r0+row)*DM + gch*8, &As[q*512]);
    }
  }
  // ---- stage B round 0 (nt=0, kt=0) ----
  #pragma unroll
  for(int m=0;m<4;m++){
    int row = w*32 + m*8 + rIn;
    gload16(WT + (int64_t)row*DM + gB*8, &Bs[0][(w*32+m*8)*64]);
  }
  __syncthreads();

  uint2 rqk[4][2][4];   // packed results nt0..3 (Q,K)
  uint2 rvg[4][2][4];   // packed results nt4..7 (V,G)

  #pragma unroll
  for(int nt=0; nt<8; nt++){
    f32x4 acc[4][2] = {};             // [j][i], swapped: regs = 4 consecutive cols
    #pragma unroll
    for(int kt=0; kt<4; kt++){
      int r = nt*4 + kt;
      int buf = r&1;
      // prefetch next round's B half
      if(r < 31){
        int rn = r+1, ntn = rn>>2, ktn = rn&3;
        #pragma unroll
        for(int m=0;m<4;m++){
          int row = w*32 + m*8 + rIn;
          gload16(WT + (int64_t)(ntn*128+row)*DM + ktn*64 + gB*8,
                  &Bs[rn&1][(w*32+m*8)*64]);
        }
      }
      // compute on Bs[buf]
      #pragma unroll
      for(int ks2=0; ks2<2; ks2++){
        bf16x8 af[2], bfv[4];
        #pragma unroll
        for(int i=0;i<2;i++){
          int rw = mw+i*16+ln15;
          int ca = (kt*8 + ks2*4 + quad) ^ (rw&7);
          af[i] = *(const bf16x8*)&As[rw*256 + ca*8];
        }
        #pragma unroll
        for(int j=0;j<4;j++){
          int rw = nw+j*16+ln15;
          int cb = (ks2*4+quad) ^ (rw&7);
          bfv[j] = *(const bf16x8*)&Bs[buf][rw*64 + cb*8];
        }
        #pragma unroll
        for(int j=0;j<4;j++)
          #pragma unroll
          for(int i=0;i<2;i++)
            acc[j][i] = __builtin_amdgcn_mfma_f32_16x16x32_bf16(bfv[j], af[i], acc[j][i], 0,0,0);
      }
      // postprocess + pack after last kt of this nt (before this round's barrier)
      if(kt==3){
        int mode = nt>>1;
        #pragma unroll
        for(int i=0;i<2;i++){
          int64_t rr = r0 + mw + i*16 + ln15;
          #pragma unroll
          for(int j=0;j<4;j++){
            int cmn = nw + j*16 + quad*4;            // col within this nt (0..127)
            float v0=acc[j][i][0], v1=acc[j][i][1], v2=acc[j][i][2], v3=acc[j][i][3];
            if(mode==0){
              float s4 = sw[rr*NH + nt*4 + (cmn>>5)];
              v0*=s4; v1*=s4; v2*=s4; v3*=s4;
            } else if(mode==1){
              v0*=SCALE; v1*=SCALE; v2*=SCALE; v3*=SCALE;
            } else if(mode==3){
              int cm0 = (nt&1)*128 + cmn;
              float4 bgv = *(const float4*)(bg + cm0);
              v0 = 1.f/(1.f+__expf(-(v0+bgv.x)));
              v1 = 1.f/(1.f+__expf(-(v1+bgv.y)));
              v2 = 1.f/(1.f+__expf(-(v2+bgv.z)));
              v3 = 1.f/(1.f+__expf(-(v3+bgv.w)));
            }
            if(nt<4) rqk[nt][i][j] = pack4(v0,v1,v2,v3);
            else     rvg[nt-4][i][j] = pack4(v0,v1,v2,v3);
          }
        }
        // flush Q,K after nt3 (one-time store drain at the next barrier)
        if(nt==3){
          #pragma unroll
          for(int n2=0;n2<4;n2++){
            u16* dst = (n2<2) ? qb : kb;
            #pragma unroll
            for(int i=0;i<2;i++){
              int64_t rr = r0 + mw + i*16 + ln15;
              #pragma unroll
              for(int j=0;j<4;j++){
                int cm0 = (n2&1)*128 + nw + j*16 + quad*4;
                *(uint2*)(dst + rr*DM + cm0) = rqk[n2][i][j];
              }
            }
          }
        }
      }
      __syncthreads();   // drains prefetched loads (flew under compute)
    }
  }

  // ---- final flush: V (scatter) + G (wide) — after last barrier ----
  {
    int s = bx/6, kpb = (bx%6)*64;
    #pragma unroll
    for(int n2=0;n2<2;n2++){          // nt4,5 -> V
      #pragma unroll
      for(int i=0;i<2;i++){
        int kpos = kpb + mw + i*16 + ln15;
        #pragma unroll
        for(int j=0;j<4;j++){
          int cmv = n2*128 + nw + j*16 + quad*4;
          uint2 pv = rvg[n2][i][j];
          u16 u0=(u16)(pv.x&0xffff), u1=(u16)(pv.x>>16);
          u16 u2=(u16)(pv.y&0xffff), u3=(u16)(pv.y>>16);
          int hh0 = (cmv+0)>>5, d0v = (cmv+0)&31;
          int hh1 = (cmv+1)>>5, d1v = (cmv+1)&31;
          int hh2 = (cmv+2)>>5, d2v = (cmv+2)&31;
          int hh3 = (cmv+3)>>5, d3v = (cmv+3)&31;
          VT[((int64_t)(hh0*NSEQ+s)*DHD + d0v)*LSEQ + kpos] = u0;
          VT[((int64_t)(hh1*NSEQ+s)*DHD + d1v)*LSEQ + kpos] = u1;
          VT[((int64_t)(hh2*NSEQ+s)*DHD + d2v)*LSEQ + kpos] = u2;
          VT[((int64_t)(hh3*NSEQ+s)*DHD + d3v)*LSEQ + kpos] = u3;
        }
      }
    }
    #pragma unroll
    for(int n2=2;n2<4;n2++){          // nt6,7 -> G
      #pragma unroll
      for(int i=0;i<2;i++){
        int64_t rr = r0 + mw + i*16 + ln15;
        #pragma unroll
        for(int j=0;j<4;j++){
          int cm0 = ((n2-2)&1)*128 + nw + j*16 + quad*4;
          *(uint2*)(gbuf + rr*DM + cm0) = rvg[n2][i][j];
        }
      }
    }
  }
}

// ---------------- K7: scores slab sc: S[h][q][k] += Q.K over s-chunk -------
// T3 prefetch: double-buffered LDS, single barrier per round, stores only at end.
__global__ __launch_bounds__(256) void k_scores(const u16* __restrict__ Q,
    const u16* __restrict__ K, float* __restrict__ scores){
  __shared__ short As[2][128*64];
  __shared__ short Bs[2][128*64];
  int t = threadIdx.x;
  int w = t>>6, lane = t&63, ln15 = lane&15, quad = lane>>4;
  int rIn = lane>>3, cch = lane&7;
  int mw = (w>>1)*64, nw = (w&1)*64;
  int q0 = blockIdx.x*128, k0t = blockIdx.y*128;
  int h = blockIdx.z>>2, sc = blockIdx.z&3;
  int g = cch ^ rIn;
  int s_off = g>>2, d16 = g&3;

  auto STAGE = [&](int i2, int bsel){
    int sb = sc*64 + i2*2 + s_off;
    #pragma unroll
    for(int ti=0; ti<4; ti++){
      int row = w*32 + ti*8 + rIn;
      gload16(Q + ((int64_t)sb*LSEQ + q0 + row)*DM + h*DHD + d16*8, &As[bsel][(w*32+ti*8)*64]);
      gload16(K + ((int64_t)sb*LSEQ + k0t + row)*DM + h*DHD + d16*8, &Bs[bsel][(w*32+ti*8)*64]);
    }
  };

  f32x4 acc[4][4] = {};
  STAGE(0, 0);
  __syncthreads();
  for(int i2=0; i2<32; i2++){
    int buf = i2&1;
    if(i2<31) STAGE(i2+1, buf^1);
    #pragma unroll
    for(int kk=0;kk<2;kk++){
      int p = (kk*4+quad) ^ (lane&7);
      bf16x8 af[4], bfv[4];
      #pragma unroll
      for(int i=0;i<4;i++) af[i]  = *(const bf16x8*)&As[buf][(mw+i*16+ln15)*64 + p*8];
      #pragma unroll
      for(int j=0;j<4;j++) bfv[j] = *(const bf16x8*)&Bs[buf][(nw+j*16+ln15)*64 + p*8];
      #pragma unroll
      for(int i=0;i<4;i++)
        #pragma unroll
        for(int j=0;j<4;j++)
          acc[i][j] = __builtin_amdgcn_mfma_f32_16x16x32_bf16(af[i], bfv[j], acc[i][j], 0,0,0);
    }
    __syncthreads();
  }
  int64_t slab = (int64_t)sc*NH*LL;
  #pragma unroll
  for(int i=0;i<4;i++)
    #pragma unroll
    for(int reg=0;reg<4;reg++){
      int q = q0 + mw + i*16 + quad*4 + reg;
      float* rp = scores + slab + ((int64_t)h*LSEQ + q)*LSEQ + k0t + nw + ln15;
      #pragma unroll
      for(int j=0;j<4;j++) rp[j*16] = acc[i][j][reg];
    }
}

// ---------------- K8: sum slabs + bias, softmax over k -> P bf16 -----------
__global__ __launch_bounds__(128) void k_softmax(const float* __restrict__ scores,
    const float* __restrict__ bias, u16* __restrict__ Pb){
  int hq = blockIdx.x, t = threadIdx.x;
  int64_t base = (int64_t)hq*LSEQ;
  float v[3];
  #pragma unroll
  for(int i=0;i<3;i++){
    int k = t + i*128;
    float x = bias[base+k];
    x += scores[base+k];
    x += scores[(int64_t)1*NH*LL + base + k];
    x += scores[(int64_t)2*NH*LL + base + k];
    x += scores[(int64_t)3*NH*LL + base + k];
    v[i]=x;
  }
  __shared__ float red[2], red2[2];
  int wv=t>>6, ln=t&63;
  float m = fmaxf(fmaxf(v[0],v[1]),v[2]);
  m = wmax(m);
  if(ln==0) red[wv]=m;
  __syncthreads();
  m = fmaxf(red[0],red[1]);
  float e = __expf(v[0]-m)+__expf(v[1]-m)+__expf(v[2]-m);
  e = wsum(e);
  if(ln==0) red2[wv]=e;
  __syncthreads();
  float inv = 1.f/(red2[0]+red2[1]);
  #pragma unroll
  for(int i=0;i<3;i++) Pb[base + t + i*128] = f2b(__expf(v[i]-m)*inv);
}

// ---------------- K9: PV. C[(s,d)][q] = sum_k VT[h][(s,d)][k] * P[h][q][k] --
__global__ __launch_bounds__(256) void k_pv(const u16* __restrict__ VT,
    const u16* __restrict__ Pb, const u16* __restrict__ gbuf,
    u16* __restrict__ attn){
  __shared__ short As[128*64];
  __shared__ short Bs[128*64];
  int t = threadIdx.x;
  int w = t>>6, lane = t&63, ln15 = lane&15, quad = lane>>4;
  int rIn = lane>>3, cch = lane&7;
  int mw = (w>>1)*64, nw = (w&1)*64;
  int mx = blockIdx.x, ny = blockIdx.y, h = blockIdx.z;
  int g = cch ^ rIn;
  f32x4 acc[4][4] = {};
  for(int it=0; it<6; it++){
    int k0 = it*64;
    __syncthreads();
    #pragma unroll
    for(int ti=0; ti<4; ti++){
      int row = w*32 + ti*8 + rIn;
      gload16(VT + ((int64_t)h*8192 + mx*128 + row)*LSEQ + k0 + g*8, &As[(w*32+ti*8)*64]);
      gload16(Pb + ((int64_t)h*LSEQ + ny*128 + row)*LSEQ + k0 + g*8, &Bs[(w*32+ti*8)*64]);
    }
    __syncthreads();
    #pragma unroll
    for(int kk=0;kk<2;kk++){
      int p = (kk*4+quad) ^ (lane&7);
      bf16x8 af[4], bfv[4];
      #pragma unroll
      for(int i=0;i<4;i++) af[i]  = *(const bf16x8*)&As[(mw+i*16+ln15)*64 + p*8];
      #pragma unroll
      for(int j=0;j<4;j++) bfv[j] = *(const bf16x8*)&Bs[(nw+j*16+ln15)*64 + p*8];
      #pragma unroll
      for(int i=0;i<4;i++)
        #pragma unroll
        for(int j=0;j<4;j++)
          acc[i][j] = __builtin_amdgcn_mfma_f32_16x16x32_bf16(af[i], bfv[j], acc[i][j], 0,0,0);
    }
  }
  #pragma unroll
  for(int i=0;i<4;i++){
    int m0 = mx*128 + mw + i*16 + quad*4;
    int s = m0>>5, d0 = m0&31;
    #pragma unroll
    for(int j=0;j<4;j++){
      int q = ny*128 + nw + j*16 + ln15;
      int64_t base = ((int64_t)s*LSEQ + q)*DM + h*DHD + d0;
      ushort4 gv = *(const ushort4*)(gbuf + base);
      ushort4 o;
      o.x = f2b(acc[i][j][0]*b2f(gv.x));
      o.y = f2b(acc[i][j][1]*b2f(gv.y));
      o.z = f2b(acc[i][j][2]*b2f(gv.z));
      o.w = f2b(acc[i][j][3]*b2f(gv.w));
      *(ushort4*)(attn + base) = o;
    }
  }
}

// ---------------- K10: out = attnout @ wo + bo (fp32 out) ------------------
// v6 structure: As once, Bs 2x16 KB T3 prefetch, both nt results held in
// registers, single store phase at kernel end.
__global__ __launch_bounds__(256,2) void k_final(const u16* __restrict__ A,
    const u16* __restrict__ WOT, const float* __restrict__ bo,
    float* __restrict__ out){
  __shared__ short As[64*256];        // 32 KB
  __shared__ short Bs[2][128*64];     // 2 x 16 KB
  int t = threadIdx.x;
  int w = t>>6, lane = t&63, ln15 = lane&15, quad = lane>>4;
  int mw = (w>>1)*32, nw = (w&1)*64;
  int64_t r0 = (int64_t)blockIdx.x*64;
  int rIn = lane>>3, cch = lane&7;
  int gB = cch ^ rIn;

  {
    int rowl = lane>>5, pc = lane&31;
    #pragma unroll
    for(int m=0;m<8;m++){
      int q = w*8+m;
      int row = 2*q + rowl;
      int gch = pc ^ (row&7);
      gload16(A + (r0+row)*DM + gch*8, &As[q*512]);
    }
  }
  #pragma unroll
  for(int m=0;m<4;m++){
    int row = w*32 + m*8 + rIn;
    gload16(WOT + (int64_t)row*DM + gB*8, &Bs[0][(w*32+m*8)*64]);
  }
  __syncthreads();

  f32x4 res[2][4][2];                 // [nt][j][i]
  #pragma unroll
  for(int nt=0; nt<2; nt++){
    f32x4 acc[4][2] = {};
    #pragma unroll
    for(int kt=0; kt<4; kt++){
      int r = nt*4 + kt;
      int buf = r&1;
      if(r < 7){
        int rn = r+1, ntn = rn>>2, ktn = rn&3;
        #pragma unroll
        for(int m=0;m<4;m++){
          int row = w*32 + m*8 + rIn;
          gload16(WOT + (int64_t)(ntn*128+row)*DM + ktn*64 + gB*8,
                  &Bs[rn&1][(w*32+m*8)*64]);
        }
      }
      #pragma unroll
      for(int ks2=0; ks2<2; ks2++){
        bf16x8 af[2], bfv[4];
        #pragma unroll
        for(int i=0;i<2;i++){
          int rw = mw+i*16+ln15;
          int ca = (kt*8 + ks2*4 + quad) ^ (rw&7);
          af[i] = *(const bf16x8*)&As[rw*256 + ca*8];
        }
        #pragma unroll
        for(int j=0;j<4;j++){
          int rw = nw+j*16+ln15;
          int cb = (ks2*4+quad) ^ (rw&7);
          bfv[j] = *(const bf16x8*)&Bs[buf][rw*64 + cb*8];
        }
        #pragma unroll
        for(int j=0;j<4;j++)
          #pragma unroll
          for(int i=0;i<2;i++)
            acc[j][i] = __builtin_amdgcn_mfma_f32_16x16x32_bf16(bfv[j], af[i], acc[j][i], 0,0,0);
      }
      __syncthreads();
    }
    #pragma unroll
    for(int j=0;j<4;j++)
      #pragma unroll
      for(int i=0;i<2;i++) res[nt][j][i] = acc[j][i];
  }

  #pragma unroll
  for(int nt=0; nt<2; nt++)
    #pragma unroll
    for(int i=0;i<2;i++){
      int64_t rr = r0 + mw + i*16 + ln15;
      #pragma unroll
      for(int j=0;j<4;j++){
        int cm0 = nt*128 + nw + j*16 + quad*4;
        float4 bv = *(const float4*)(bo + cm0);
        float4 o;
        o.x = res[nt][j][i][0] + bv.x;
        o.y = res[nt][j][i][1] + bv.y;
        o.z = res[nt][j][i][2] + bv.z;
        o.w = res[nt][j][i][3] + bv.w;
        *(float4*)(out + rr*DM + cm0) = o;
      }
    }
}

extern "C" void kernel_launch(void* const* d_in, const int* in_sizes, int n_in,
                              void* d_out, int out_size, void* d_ws, size_t ws_size,
                              hipStream_t stream){
  const float* msa    = (const float*)d_in[0];
  const float* pair   = (const float*)d_in[1];
  const float* lmg    = (const float*)d_in[2];
  const float* lmb    = (const float*)d_in[3];
  const float* lpg    = (const float*)d_in[4];
  const float* lpb    = (const float*)d_in[5];
  const float* sw_q_w = (const float*)d_in[6];
  const float* sw_q_b = (const float*)d_in[7];
  const float* sw_k_w = (const float*)d_in[8];
  // d_in[9] = sw_k_b: constant over n, cancels in softmax over n.
  const float* wq     = (const float*)d_in[10];
  const float* wk     = (const float*)d_in[11];
  const float* wv     = (const float*)d_in[12];
  const float* wb     = (const float*)d_in[13];
  const float* wg     = (const float*)d_in[14];
  const float* bg     = (const float*)d_in[15];
  const float* wo     = (const float*)d_in[16];
  const float* bo     = (const float*)d_in[17];
  float* out = (float*)d_out;

  // workspace layout (~285 MB)
  u16* msa_n = (u16*)d_ws;                       // [NL][256] bf16
  u16* qb    = msa_n + (int64_t)NL*DM;
  u16* kb    = qb + (int64_t)NL*DM;
  u16* gbuf  = kb + (int64_t)NL*DM;
  u16* VT    = gbuf + (int64_t)NL*DM;            // [8][256][32][384] bf16
  u16* Pb    = VT + (int64_t)NL*DM;              // [8][384][384] bf16
  u16* WTall = Pb + (int64_t)NH*LSEQ*LSEQ;       // [1024][256] bf16
  u16* WOT   = WTall + 1024*DM;                  // [256][256] bf16
  float* u_buf = (float*)(WOT + DM*DM);          // [384][8][256] f32
  float* sw  = u_buf + (int64_t)LSEQ*NH*DM;      // [256*384][8] f32
  float* bias = sw + (int64_t)NL*NH;             // [8][384][384] f32
  float* scores = bias + (int64_t)NH*LL;         // 4 slabs [8][384][384] f32
  u16* attnout = msa_n;                          // alias: msa_n dead after proj

  k_ln_msa<<<NL/4, 256, 0, stream>>>(msa, lmg, lmb, msa_n);
  k_wconv<<<dim3(4,4,5), 256, 0, stream>>>(wq, wk, wv, wg, wo, WTall, WOT);
  k_u<<<LSEQ, 256, 0, stream>>>(msa_n, sw_q_w, sw_q_b, sw_k_w, u_buf);
  k_seqw<<<LSEQ, 256, 0, stream>>>(msa_n, u_buf, sw);
  k_bias<<<LL/256, 256, 0, stream>>>(pair, lpg, lpb, wb, bias);
  k_projf<<<dim3(NL/64), 256, 0, stream>>>(msa_n, WTall, qb, kb, gbuf, VT, sw, bg);
  k_scores<<<dim3(3,3,32), 256, 0, stream>>>(qb, kb, scores);
  k_softmax<<<NH*LSEQ, 128, 0, stream>>>(scores, bias, Pb);
  k_pv<<<dim3(64,3,NH), 256, 0, stream>>>(VT, Pb, gbuf, attnout);
  k_final<<<dim3(NL/64), 256, 0, stream>>>(attnout, WOT, bo, out);
}

// Round 8
// 661.054 us; speedup vs baseline: 1.1479x; 1.0020x over previous
//
#include <hip/hip_runtime.h>
#include <hip/hip_fp16.h>
#include <stdint.h>

#define NSEQ 256
#define LSEQ 384
#define DM   256
#define DP   128
#define NH   8
#define DHD  32
#define NL   (NSEQ*LSEQ)   /* 98304 */
#define LL   (LSEQ*LSEQ)   /* 147456 */
#define SCALE 0.17677669529663687f

typedef unsigned short u16;
typedef short bf16x8 __attribute__((ext_vector_type(8)));
typedef float f32x4 __attribute__((ext_vector_type(4)));

__device__ __forceinline__ float b2f(u16 s){
  union { uint32_t u; float f; } v; v.u = ((uint32_t)s)<<16; return v.f;
}
__device__ __forceinline__ u16 f2b(float f){
  union { float f; uint32_t u; } v; v.f = f;
  uint32_t u = v.u;
  return (u16)((u + 0x7FFFu + ((u>>16)&1u)) >> 16);
}
__device__ __forceinline__ uint2 pack4(float a,float b,float c,float d){
  uint2 r;
  r.x = (uint32_t)f2b(a) | ((uint32_t)f2b(b)<<16);
  r.y = (uint32_t)f2b(c) | ((uint32_t)f2b(d)<<16);
  return r;
}
__device__ __forceinline__ float wsum(float x){
  #pragma unroll
  for(int o=32;o>0;o>>=1) x += __shfl_xor(x,o,64);
  return x;
}
__device__ __forceinline__ float wmax(float x){
  #pragma unroll
  for(int o=32;o>0;o>>=1) x = fmaxf(x, __shfl_xor(x,o,64));
  return x;
}
// async 16B global->LDS. LDS dest = wave-uniform base + lane*16.
__device__ __forceinline__ void gload16(const void* g, void* l){
  __builtin_amdgcn_global_load_lds((const __attribute__((address_space(1))) void*)g,
      (__attribute__((address_space(3))) void*)l, 16, 0, 0);
}

// counted-wait + barrier as ONE asm block: nothing (stage intrinsics,
// ds_reads) can be migrated across it by the compiler (memory clobber),
// and the wave waits its OWN vmcnt BEFORE publishing at the barrier.
#define WAITBAR(N) asm volatile("s_waitcnt vmcnt(" #N ")\n\ts_barrier" ::: "memory")

// ---------------- K1: LayerNorm(msa) -> bf16, wave per row ----------------
__global__ __launch_bounds__(256) void k_ln_msa(const float* __restrict__ msa,
    const float* __restrict__ g, const float* __restrict__ b, u16* __restrict__ out){
  int lane = threadIdx.x & 63;
  int64_t row = (int64_t)blockIdx.x*4 + (threadIdx.x>>6);
  const float4 x = *(const float4*)(msa + row*DM + lane*4);
  float s = x.x+x.y+x.z+x.w;
  float q = x.x*x.x+x.y*x.y+x.z*x.z+x.w*x.w;
  s = wsum(s); q = wsum(q);
  float mean = s*(1.0f/DM);
  float rstd = rsqrtf(q*(1.0f/DM) - mean*mean + 1e-5f);
  int c = lane*4;
  float4 gv = *(const float4*)(g+c);
  float4 bv = *(const float4*)(b+c);
  ushort4 o;
  o.x=f2b((x.x-mean)*rstd*gv.x+bv.x);
  o.y=f2b((x.y-mean)*rstd*gv.y+bv.y);
  o.z=f2b((x.z-mean)*rstd*gv.z+bv.z);
  o.w=f2b((x.w-mean)*rstd*gv.w+bv.w);
  *(ushort4*)(out + row*DM + c) = o;
}

// ---------------- K2: weight convert+transpose fp32 -> bf16 ----------------
__global__ __launch_bounds__(256) void k_wconv(const float* __restrict__ wq,
    const float* __restrict__ wk, const float* __restrict__ wv,
    const float* __restrict__ wg, const float* __restrict__ wo,
    u16* __restrict__ WTall, u16* __restrict__ WOT){
  __shared__ float tile[64][65];
  int z = blockIdx.z;
  const float* src = (z==0)?wq:(z==1)?wk:(z==2)?wv:(z==3)?wg:wo;
  u16* dst = (z<4) ? (WTall + z*DM*DM) : WOT;
  int k0 = blockIdx.x*64, n0 = blockIdx.y*64, t = threadIdx.x;
  int r = t>>4, c4 = (t&15)*4;
  #pragma unroll
  for(int it=0; it<4; it++){
    float4 v = *(const float4*)(src + (int64_t)(k0 + it*16 + r)*DM + n0 + c4);
    tile[it*16+r][c4+0]=v.x; tile[it*16+r][c4+1]=v.y;
    tile[it*16+r][c4+2]=v.z; tile[it*16+r][c4+3]=v.w;
  }
  __syncthreads();
  #pragma unroll
  for(int it=0; it<4; it++){
    int nl = it*16 + r, kl = c4;
    ushort4 o;
    o.x=f2b(tile[kl+0][nl]); o.y=f2b(tile[kl+1][nl]);
    o.z=f2b(tile[kl+2][nl]); o.w=f2b(tile[kl+3][nl]);
    *(ushort4*)(dst + (int64_t)(n0+nl)*DM + k0 + kl) = o;
  }
}

// ---------------- K3: u[l,h,c] = sum_d sw_k_w[c,h*32+d] * swq[l,h,d] -------
__global__ __launch_bounds__(256) void k_u(const u16* __restrict__ msa_n,
    const float* __restrict__ sw_q_w, const float* __restrict__ sw_q_b,
    const float* __restrict__ sw_k_w, float* __restrict__ u){
  __shared__ float tar[DM];
  __shared__ float swq[DM];
  int l = blockIdx.x, t = threadIdx.x;
  tar[t] = b2f(msa_n[(int64_t)l*DM + t]);
  __syncthreads();
  float acc = sw_q_b[t];
  for(int c=0;c<DM;c++) acc += tar[c]*sw_q_w[c*DM + t];
  swq[t] = acc * SCALE;
  __syncthreads();
  float res[NH];
  #pragma unroll
  for(int h=0;h<NH;h++){
    float a = 0.f;
    #pragma unroll
    for(int d=0;d<DHD;d+=4){
      float4 w = *(const float4*)(sw_k_w + t*DM + h*DHD + d);
      a += w.x*swq[h*DHD+d] + w.y*swq[h*DHD+d+1] + w.z*swq[h*DHD+d+2] + w.w*swq[h*DHD+d+3];
    }
    res[h]=a;
  }
  #pragma unroll
  for(int h=0;h<NH;h++) u[((int64_t)l*NH + h)*DM + t] = res[h];
}

// ---------------- K4: sw_logits + softmax over n -> seq_weight[n,l,h] ------
__global__ __launch_bounds__(256) void k_seqw(const u16* __restrict__ msa_n,
    const float* __restrict__ u, float* __restrict__ sw){
  __shared__ float ul[NH*DM];
  __shared__ float lg[NH*256];
  __shared__ float mx[NH], sm[NH];
  int l = blockIdx.x, t = threadIdx.x;
  #pragma unroll
  for(int h=0;h<NH;h++) ul[h*DM+t] = u[((int64_t)l*NH+h)*DM + t];
  __syncthreads();
  float acc[NH] = {};
  const u16* row = msa_n + ((int64_t)t*LSEQ + l)*DM;   // n = t
  for(int c=0;c<DM;c+=4){
    ushort4 xv = *(const ushort4*)(row + c);
    float x0=b2f(xv.x), x1=b2f(xv.y), x2=b2f(xv.z), x3=b2f(xv.w);
    #pragma unroll
    for(int h=0;h<NH;h++)
      acc[h] += x0*ul[h*DM+c] + x1*ul[h*DM+c+1] + x2*ul[h*DM+c+2] + x3*ul[h*DM+c+3];
  }
  #pragma unroll
  for(int h=0;h<NH;h++) lg[h*256+t] = acc[h];
  __syncthreads();
  int wv = t>>6, ln = t&63;
  for(int h=wv; h<NH; h+=4){
    float a=lg[h*256+ln], b=lg[h*256+ln+64], c=lg[h*256+ln+128], d=lg[h*256+ln+192];
    float m = wmax(fmaxf(fmaxf(a,b),fmaxf(c,d)));
    float e = __expf(a-m)+__expf(b-m)+__expf(c-m)+__expf(d-m);
    e = wsum(e);
    if(ln==0){ mx[h]=m; sm[h]=1.f/e; }
  }
  __syncthreads();
  float o[NH];
  #pragma unroll
  for(int h=0;h<NH;h++) o[h] = __expf(acc[h]-mx[h])*sm[h];
  float* dst = sw + ((int64_t)t*LSEQ + l)*NH;
  *(float4*)dst     = make_float4(o[0],o[1],o[2],o[3]);
  *(float4*)(dst+4) = make_float4(o[4],o[5],o[6],o[7]);
}

// ---------------- K5: bias[h][q][k] = LN(pair[q,k,:]) @ wb -----------------
__global__ __launch_bounds__(256) void k_bias(const float* __restrict__ pair,
    const float* __restrict__ g, const float* __restrict__ b,
    const float* __restrict__ wb, float* __restrict__ bias){
  int64_t row = (int64_t)blockIdx.x*256 + threadIdx.x;   // over L*L
  const float* pr = pair + row*DP;
  uint2 xs[32];                       // 128 channels as packed fp16
  float s = 0.f, q = 0.f;
  #pragma unroll
  for(int i=0;i<32;i++){
    float4 v = *(const float4*)(pr + i*4);
    s += v.x+v.y+v.z+v.w;
    q += v.x*v.x+v.y*v.y+v.z*v.z+v.w*v.w;
    __half2 p0 = __floats2half2_rn(v.x, v.y);
    __half2 p1 = __floats2half2_rn(v.z, v.w);
    xs[i].x = *(const uint32_t*)&p0;
    xs[i].y = *(const uint32_t*)&p1;
  }
  float mean = s*(1.f/DP);
  float rstd = rsqrtf(q*(1.f/DP) - mean*mean + 1e-5f);
  float acc[NH] = {};
  #pragma unroll
  for(int i=0;i<32;i++){
    __half2 p0 = *(const __half2*)&xs[i].x;
    __half2 p1 = *(const __half2*)&xs[i].y;
    float2 f0 = __half22float2(p0);
    float2 f1 = __half22float2(p1);
    float xv[4] = {f0.x, f0.y, f1.x, f1.y};
    #pragma unroll
    for(int c4=0;c4<4;c4++){
      int c = i*4 + c4;
      float y = (xv[c4]-mean)*rstd*g[c] + b[c];
      #pragma unroll
      for(int h=0;h<NH;h++) acc[h] += y*wb[c*NH+h];
    }
  }
  #pragma unroll
  for(int h=0;h<NH;h++) bias[(int64_t)h*LL + row] = acc[h];
}

// ==================== MFMA cores ============================================
// v7: counted-vmcnt depth-3 pipelines (T4, m201 publish discipline).
// Per round: stage B[r+2] into slot freed by this round's opening barrier;
// compute slot r%3; then `s_waitcnt vmcnt(4); s_barrier` — wait own B[r+1]
// BEFORE the barrier, leave B[r+2] in flight ACROSS it. Loads get ~2 rounds
// of flight instead of <1. Q/K flush issued at start of round 16 so the
// always-N=4 wait is store-count-robust. 80 KB LDS -> 2 blocks/CU.

// ---------------- K6: fused projection, one block per 64-row strip ---------
__global__ __launch_bounds__(256,2) void k_projf(const u16* __restrict__ A,
    const u16* __restrict__ WT, u16* __restrict__ qb, u16* __restrict__ kb,
    u16* __restrict__ gbuf, u16* __restrict__ VT,
    const float* __restrict__ sw, const float* __restrict__ bg){
  __shared__ short As[64*256];        // 32 KB
  __shared__ short Bs[3][128*64];     // 3 x 16 KB ring
  int t = threadIdx.x;
  int w = t>>6, lane = t&63, ln15 = lane&15, quad = lane>>4;
  int mw = (w>>1)*32, nw = (w&1)*64;
  int bx = blockIdx.x;                // 0..1535 row strip
  int64_t r0 = (int64_t)bx*64;
  int rIn = lane>>3, cch = lane&7;
  int gB = cch ^ rIn;                 // B-stage swizzled chunk (row&7==rIn)

  // ---- prologue: stage A (8/wave) + B rounds 0,1 (4/wave each) ----
  {
    int rowl = lane>>5, pc = lane&31;
    #pragma unroll
    for(int m=0;m<8;m++){
      int q = w*8+m;
      int row = 2*q + rowl;
      int gch = pc ^ (row&7);
      gload16(A + (r0+row)*DM + gch*8, &As[q*512]);
    }
  }
  #pragma unroll
  for(int rr=0;rr<2;rr++){
    int ntn = rr>>2, ktn = rr&3;
    #pragma unroll
    for(int m=0;m<4;m++){
      int row = w*32 + m*8 + rIn;
      gload16(WT + (int64_t)(ntn*128+row)*DM + ktn*64 + gB*8, &Bs[rr][(w*32+m*8)*64]);
    }
  }
  WAITBAR(4);                         // A+B0 landed (all waves); B1 in flight

  uint2 rqk[4][2][4];   // packed results nt0..3 (Q,K)
  uint2 rvg[4][2][4];   // packed results nt4..7 (V,G)

  #pragma unroll
  for(int nt=0; nt<8; nt++){
    f32x4 acc[4][2] = {};             // [j][i], swapped: regs = 4 consecutive cols
    #pragma unroll
    for(int kt=0; kt<4; kt++){
      const int r = nt*4 + kt;
      // Q/K flush: start of round 16 (after r15's barrier). FIFO order
      // [B17, stores, B18] so the N=4 wait at end of r16 is always safe.
      if(nt==4 && kt==0){
        #pragma unroll
        for(int n2=0;n2<4;n2++){
          u16* dst = (n2<2) ? qb : kb;
          #pragma unroll
          for(int i=0;i<2;i++){
            int64_t rr = r0 + mw + i*16 + ln15;
            #pragma unroll
            for(int j=0;j<4;j++){
              int cm0 = (n2&1)*128 + nw + j*16 + quad*4;
              *(uint2*)(dst + rr*DM + cm0) = rqk[n2][i][j];
            }
          }
        }
      }
      // stage B[r+2] into slot (r+2)%3 (freed by this round's opening barrier)
      if(r+2 <= 31){
        const int rn = r+2, ntn = rn>>2, ktn = rn&3, sl = rn%3;
        #pragma unroll
        for(int m=0;m<4;m++){
          int row = w*32 + m*8 + rIn;
          gload16(WT + (int64_t)(ntn*128+row)*DM + ktn*64 + gB*8, &Bs[sl][(w*32+m*8)*64]);
        }
      }
      // compute on slot r%3
      {
        const int sl = r%3;
        #pragma unroll
        for(int ks2=0; ks2<2; ks2++){
          bf16x8 af[2], bfv[4];
          #pragma unroll
          for(int i=0;i<2;i++){
            int rw = mw+i*16+ln15;
            int ca = (kt*8 + ks2*4 + quad) ^ (rw&7);
            af[i] = *(const bf16x8*)&As[rw*256 + ca*8];
          }
          #pragma unroll
          for(int j=0;j<4;j++){
            int rw = nw+j*16+ln15;
            int cb = (ks2*4+quad) ^ (rw&7);
            bfv[j] = *(const bf16x8*)&Bs[sl][rw*64 + cb*8];
          }
          #pragma unroll
          for(int j=0;j<4;j++)
            #pragma unroll
            for(int i=0;i<2;i++)
              acc[j][i] = __builtin_amdgcn_mfma_f32_16x16x32_bf16(bfv[j], af[i], acc[j][i], 0,0,0);
        }
      }
      // postprocess + pack after last kt of this nt
      if(kt==3){
        int mode = nt>>1;
        #pragma unroll
        for(int i=0;i<2;i++){
          int64_t rr = r0 + mw + i*16 + ln15;
          #pragma unroll
          for(int j=0;j<4;j++){
            int cmn = nw + j*16 + quad*4;            // col within this nt (0..127)
            float v0=acc[j][i][0], v1=acc[j][i][1], v2=acc[j][i][2], v3=acc[j][i][3];
            if(mode==0){
              float s4 = sw[rr*NH + nt*4 + (cmn>>5)];
              v0*=s4; v1*=s4; v2*=s4; v3*=s4;
            } else if(mode==1){
              v0*=SCALE; v1*=SCALE; v2*=SCALE; v3*=SCALE;
            } else if(mode==3){
              int cm0 = (nt&1)*128 + cmn;
              float4 bgv = *(const float4*)(bg + cm0);
              v0 = 1.f/(1.f+__expf(-(v0+bgv.x)));
              v1 = 1.f/(1.f+__expf(-(v1+bgv.y)));
              v2 = 1.f/(1.f+__expf(-(v2+bgv.z)));
              v3 = 1.f/(1.f+__expf(-(v3+bgv.w)));
            }
            if(nt<4) rqk[nt][i][j] = pack4(v0,v1,v2,v3);
            else     rvg[nt-4][i][j] = pack4(v0,v1,v2,v3);
          }
        }
      }
      // end-of-round: wait own B[r+1] (leave B[r+2] in flight), publish.
      if(r < 31){
        if(r == 30) WAITBAR(0);
        else        WAITBAR(4);
      }
    }
  }

  // ---- final flush: V (scatter) + G (wide) — after last barrier ----
  {
    int s = bx/6, kpb = (bx%6)*64;
    #pragma unroll
    for(int n2=0;n2<2;n2++){          // nt4,5 -> V
      #pragma unroll
      for(int i=0;i<2;i++){
        int kpos = kpb + mw + i*16 + ln15;
        #pragma unroll
        for(int j=0;j<4;j++){
          int cmv = n2*128 + nw + j*16 + quad*4;
          uint2 pv = rvg[n2][i][j];
          u16 u0=(u16)(pv.x&0xffff), u1=(u16)(pv.x>>16);
          u16 u2=(u16)(pv.y&0xffff), u3=(u16)(pv.y>>16);
          int hh0 = (cmv+0)>>5, d0v = (cmv+0)&31;
          int hh1 = (cmv+1)>>5, d1v = (cmv+1)&31;
          int hh2 = (cmv+2)>>5, d2v = (cmv+2)&31;
          int hh3 = (cmv+3)>>5, d3v = (cmv+3)&31;
          VT[((int64_t)(hh0*NSEQ+s)*DHD + d0v)*LSEQ + kpos] = u0;
          VT[((int64_t)(hh1*NSEQ+s)*DHD + d1v)*LSEQ + kpos] = u1;
          VT[((int64_t)(hh2*NSEQ+s)*DHD + d2v)*LSEQ + kpos] = u2;
          VT[((int64_t)(hh3*NSEQ+s)*DHD + d3v)*LSEQ + kpos] = u3;
        }
      }
    }
    #pragma unroll
    for(int n2=2;n2<4;n2++){          // nt6,7 -> G
      #pragma unroll
      for(int i=0;i<2;i++){
        int64_t rr = r0 + mw + i*16 + ln15;
        #pragma unroll
        for(int j=0;j<4;j++){
          int cm0 = ((n2-2)&1)*128 + nw + j*16 + quad*4;
          *(uint2*)(gbuf + rr*DM + cm0) = rvg[n2][i][j];
        }
      }
    }
  }
}

// ---------------- K7: scores slab sc: S[h][q][k] += Q.K over s-chunk -------
// Depth-3 counted pipeline (96 KB LDS; grid 288 blocks ~ 1/CU anyway).
__global__ __launch_bounds__(256) void k_scores(const u16* __restrict__ Q,
    const u16* __restrict__ K, float* __restrict__ scores){
  __shared__ short As[3][128*64];
  __shared__ short Bs[3][128*64];
  int t = threadIdx.x;
  int w = t>>6, lane = t&63, ln15 = lane&15, quad = lane>>4;
  int rIn = lane>>3, cch = lane&7;
  int mw = (w>>1)*64, nw = (w&1)*64;
  int q0 = blockIdx.x*128, k0t = blockIdx.y*128;
  int h = blockIdx.z>>2, sc = blockIdx.z&3;
  int g = cch ^ rIn;
  int s_off = g>>2, d16 = g&3;

  auto STAGE = [&](int i2, int bsel){
    int sb = sc*64 + i2*2 + s_off;
    #pragma unroll
    for(int ti=0; ti<4; ti++){
      int row = w*32 + ti*8 + rIn;
      gload16(Q + ((int64_t)sb*LSEQ + q0 + row)*DM + h*DHD + d16*8, &As[bsel][(w*32+ti*8)*64]);
      gload16(K + ((int64_t)sb*LSEQ + k0t + row)*DM + h*DHD + d16*8, &Bs[bsel][(w*32+ti*8)*64]);
    }
  };

  f32x4 acc[4][4] = {};
  STAGE(0, 0);
  STAGE(1, 1);
  WAITBAR(8);                         // round-0 tiles landed; round-1 in flight
  for(int i2=0; i2<32; i2++){
    int buf = i2%3;
    if(i2 < 30) STAGE(i2+2, (i2+2)%3);
    #pragma unroll
    for(int kk=0;kk<2;kk++){
      int p = (kk*4+quad) ^ (lane&7);
      bf16x8 af[4], bfv[4];
      #pragma unroll
      for(int i=0;i<4;i++) af[i]  = *(const bf16x8*)&As[buf][(mw+i*16+ln15)*64 + p*8];
      #pragma unroll
      for(int j=0;j<4;j++) bfv[j] = *(const bf16x8*)&Bs[buf][(nw+j*16+ln15)*64 + p*8];
      #pragma unroll
      for(int i=0;i<4;i++)
        #pragma unroll
        for(int j=0;j<4;j++)
          acc[i][j] = __builtin_amdgcn_mfma_f32_16x16x32_bf16(af[i], bfv[j], acc[i][j], 0,0,0);
    }
    if(i2 < 30)      WAITBAR(8);
    else if(i2 == 30) WAITBAR(0);
  }
  int64_t slab = (int64_t)sc*NH*LL;
  #pragma unroll
  for(int i=0;i<4;i++)
    #pragma unroll
    for(int reg=0;reg<4;reg++){
      int q = q0 + mw + i*16 + quad*4 + reg;
      float* rp = scores + slab + ((int64_t)h*LSEQ + q)*LSEQ + k0t + nw + ln15;
      #pragma unroll
      for(int j=0;j<4;j++) rp[j*16] = acc[i][j][reg];
    }
}

// ---------------- K8: sum slabs + bias, softmax over k -> P bf16 -----------
__global__ __launch_bounds__(128) void k_softmax(const float* __restrict__ scores,
    const float* __restrict__ bias, u16* __restrict__ Pb){
  int hq = blockIdx.x, t = threadIdx.x;
  int64_t base = (int64_t)hq*LSEQ;
  float v[3];
  #pragma unroll
  for(int i=0;i<3;i++){
    int k = t + i*128;
    float x = bias[base+k];
    x += scores[base+k];
    x += scores[(int64_t)1*NH*LL + base + k];
    x += scores[(int64_t)2*NH*LL + base + k];
    x += scores[(int64_t)3*NH*LL + base + k];
    v[i]=x;
  }
  __shared__ float red[2], red2[2];
  int wv=t>>6, ln=t&63;
  float m = fmaxf(fmaxf(v[0],v[1]),v[2]);
  m = wmax(m);
  if(ln==0) red[wv]=m;
  __syncthreads();
  m = fmaxf(red[0],red[1]);
  float e = __expf(v[0]-m)+__expf(v[1]-m)+__expf(v[2]-m);
  e = wsum(e);
  if(ln==0) red2[wv]=e;
  __syncthreads();
  float inv = 1.f/(red2[0]+red2[1]);
  #pragma unroll
  for(int i=0;i<3;i++) Pb[base + t + i*128] = f2b(__expf(v[i]-m)*inv);
}

// ---------------- K9: PV. C[(s,d)][q] = sum_k VT[h][(s,d)][k] * P[h][q][k] --
// v7: drain-0 prefetch (2-buffer, single barrier/round) — was cold 2-barrier.
__global__ __launch_bounds__(256) void k_pv(const u16* __restrict__ VT,
    const u16* __restrict__ Pb, const u16* __restrict__ gbuf,
    u16* __restrict__ attn){
  __shared__ short As[2][128*64];
  __shared__ short Bs[2][128*64];
  int t = threadIdx.x;
  int w = t>>6, lane = t&63, ln15 = lane&15, quad = lane>>4;
  int rIn = lane>>3, cch = lane&7;
  int mw = (w>>1)*64, nw = (w&1)*64;
  int mx = blockIdx.x, ny = blockIdx.y, h = blockIdx.z;
  int g = cch ^ rIn;

  auto STAGE = [&](int it, int bsel){
    int k0 = it*64;
    #pragma unroll
    for(int ti=0; ti<4; ti++){
      int row = w*32 + ti*8 + rIn;
      gload16(VT + ((int64_t)h*8192 + mx*128 + row)*LSEQ + k0 + g*8, &As[bsel][(w*32+ti*8)*64]);
      gload16(Pb + ((int64_t)h*LSEQ + ny*128 + row)*LSEQ + k0 + g*8, &Bs[bsel][(w*32+ti*8)*64]);
    }
  };

  f32x4 acc[4][4] = {};
  STAGE(0, 0);
  __syncthreads();
  for(int it=0; it<6; it++){
    int buf = it&1;
    if(it<5) STAGE(it+1, buf^1);
    #pragma unroll
    for(int kk=0;kk<2;kk++){
      int p = (kk*4+quad) ^ (lane&7);
      bf16x8 af[4], bfv[4];
      #pragma unroll
      for(int i=0;i<4;i++) af[i]  = *(const bf16x8*)&As[buf][(mw+i*16+ln15)*64 + p*8];
      #pragma unroll
      for(int j=0;j<4;j++) bfv[j] = *(const bf16x8*)&Bs[buf][(nw+j*16+ln15)*64 + p*8];
      #pragma unroll
      for(int i=0;i<4;i++)
        #pragma unroll
        for(int j=0;j<4;j++)
          acc[i][j] = __builtin_amdgcn_mfma_f32_16x16x32_bf16(af[i], bfv[j], acc[i][j], 0,0,0);
    }
    __syncthreads();
  }
  #pragma unroll
  for(int i=0;i<4;i++){
    int m0 = mx*128 + mw + i*16 + quad*4;
    int s = m0>>5, d0 = m0&31;
    #pragma unroll
    for(int j=0;j<4;j++){
      int q = ny*128 + nw + j*16 + ln15;
      int64_t base = ((int64_t)s*LSEQ + q)*DM + h*DHD + d0;
      ushort4 gv = *(const ushort4*)(gbuf + base);
      ushort4 o;
      o.x = f2b(acc[i][j][0]*b2f(gv.x));
      o.y = f2b(acc[i][j][1]*b2f(gv.y));
      o.z = f2b(acc[i][j][2]*b2f(gv.z));
      o.w = f2b(acc[i][j][3]*b2f(gv.w));
      *(ushort4*)(attn + base) = o;
    }
  }
}

// ---------------- K10: out = attnout @ wo + bo (fp32 out) ------------------
// v7: counted depth-3 pipeline like k_projf; stores at kernel end.
__global__ __launch_bounds__(256,2) void k_final(const u16* __restrict__ A,
    const u16* __restrict__ WOT, const float* __restrict__ bo,
    float* __restrict__ out){
  __shared__ short As[64*256];        // 32 KB
  __shared__ short Bs[3][128*64];     // 3 x 16 KB ring
  int t = threadIdx.x;
  int w = t>>6, lane = t&63, ln15 = lane&15, quad = lane>>4;
  int mw = (w>>1)*32, nw = (w&1)*64;
  int64_t r0 = (int64_t)blockIdx.x*64;
  int rIn = lane>>3, cch = lane&7;
  int gB = cch ^ rIn;

  {
    int rowl = lane>>5, pc = lane&31;
    #pragma unroll
    for(int m=0;m<8;m++){
      int q = w*8+m;
      int row = 2*q + rowl;
      int gch = pc ^ (row&7);
      gload16(A + (r0+row)*DM + gch*8, &As[q*512]);
    }
  }
  #pragma unroll
  for(int rr=0;rr<2;rr++){
    int ntn = rr>>2, ktn = rr&3;
    #pragma unroll
    for(int m=0;m<4;m++){
      int row = w*32 + m*8 + rIn;
      gload16(WOT + (int64_t)(ntn*128+row)*DM + ktn*64 + gB*8, &Bs[rr][(w*32+m*8)*64]);
    }
  }
  WAITBAR(4);

  f32x4 res[2][4][2];                 // [nt][j][i]
  #pragma unroll
  for(int nt=0; nt<2; nt++){
    f32x4 acc[4][2] = {};
    #pragma unroll
    for(int kt=0; kt<4; kt++){
      const int r = nt*4 + kt;
      if(r+2 <= 7){
        const int rn = r+2, ntn = rn>>2, ktn = rn&3, sl = rn%3;
        #pragma unroll
        for(int m=0;m<4;m++){
          int row = w*32 + m*8 + rIn;
          gload16(WOT + (int64_t)(ntn*128+row)*DM + ktn*64 + gB*8, &Bs[sl][(w*32+m*8)*64]);
        }
      }
      {
        const int sl = r%3;
        #pragma unroll
        for(int ks2=0; ks2<2; ks2++){
          bf16x8 af[2], bfv[4];
          #pragma unroll
          for(int i=0;i<2;i++){
            int rw = mw+i*16+ln15;
            int ca = (kt*8 + ks2*4 + quad) ^ (rw&7);
            af[i] = *(const bf16x8*)&As[rw*256 + ca*8];
          }
          #pragma unroll
          for(int j=0;j<4;j++){
            int rw = nw+j*16+ln15;
            int cb = (ks2*4+quad) ^ (rw&7);
            bfv[j] = *(const bf16x8*)&Bs[sl][rw*64 + cb*8];
          }
          #pragma unroll
          for(int j=0;j<4;j++)
            #pragma unroll
            for(int i=0;i<2;i++)
              acc[j][i] = __builtin_amdgcn_mfma_f32_16x16x32_bf16(bfv[j], af[i], acc[j][i], 0,0,0);
        }
      }
      if(r < 7){
        if(r == 6) WAITBAR(0);
        else       WAITBAR(4);
      }
    }
    #pragma unroll
    for(int j=0;j<4;j++)
      #pragma unroll
      for(int i=0;i<2;i++) res[nt][j][i] = acc[j][i];
  }

  #pragma unroll
  for(int nt=0; nt<2; nt++)
    #pragma unroll
    for(int i=0;i<2;i++){
      int64_t rr = r0 + mw + i*16 + ln15;
      #pragma unroll
      for(int j=0;j<4;j++){
        int cm0 = nt*128 + nw + j*16 + quad*4;
        float4 bv = *(const float4*)(bo + cm0);
        float4 o;
        o.x = res[nt][j][i][0] + bv.x;
        o.y = res[nt][j][i][1] + bv.y;
        o.z = res[nt][j][i][2] + bv.z;
        o.w = res[nt][j][i][3] + bv.w;
        *(float4*)(out + rr*DM + cm0) = o;
      }
    }
}

extern "C" void kernel_launch(void* const* d_in, const int* in_sizes, int n_in,
                              void* d_out, int out_size, void* d_ws, size_t ws_size,
                              hipStream_t stream){
  const float* msa    = (const float*)d_in[0];
  const float* pair   = (const float*)d_in[1];
  const float* lmg    = (const float*)d_in[2];
  const float* lmb    = (const float*)d_in[3];
  const float* lpg    = (const float*)d_in[4];
  const float* lpb    = (const float*)d_in[5];
  const float* sw_q_w = (const float*)d_in[6];
  const float* sw_q_b = (const float*)d_in[7];
  const float* sw_k_w = (const float*)d_in[8];
  // d_in[9] = sw_k_b: constant over n, cancels in softmax over n.
  const float* wq     = (const float*)d_in[10];
  const float* wk     = (const float*)d_in[11];
  const float* wv     = (const float*)d_in[12];
  const float* wb     = (const float*)d_in[13];
  const float* wg     = (const float*)d_in[14];
  const float* bg     = (const float*)d_in[15];
  const float* wo     = (const float*)d_in[16];
  const float* bo     = (const float*)d_in[17];
  float* out = (float*)d_out;

  // workspace layout (~285 MB)
  u16* msa_n = (u16*)d_ws;                       // [NL][256] bf16
  u16* qb    = msa_n + (int64_t)NL*DM;
  u16* kb    = qb + (int64_t)NL*DM;
  u16* gbuf  = kb + (int64_t)NL*DM;
  u16* VT    = gbuf + (int64_t)NL*DM;            // [8][256][32][384] bf16
  u16* Pb    = VT + (int64_t)NL*DM;              // [8][384][384] bf16
  u16* WTall = Pb + (int64_t)NH*LSEQ*LSEQ;       // [1024][256] bf16
  u16* WOT   = WTall + 1024*DM;                  // [256][256] bf16
  float* u_buf = (float*)(WOT + DM*DM);          // [384][8][256] f32
  float* sw  = u_buf + (int64_t)LSEQ*NH*DM;      // [256*384][8] f32
  float* bias = sw + (int64_t)NL*NH;             // [8][384][384] f32
  float* scores = bias + (int64_t)NH*LL;         // 4 slabs [8][384][384] f32
  u16* attnout = msa_n;                          // alias: msa_n dead after proj

  k_ln_msa<<<NL/4, 256, 0, stream>>>(msa, lmg, lmb, msa_n);
  k_wconv<<<dim3(4,4,5), 256, 0, stream>>>(wq, wk, wv, wg, wo, WTall, WOT);
  k_u<<<LSEQ, 256, 0, stream>>>(msa_n, sw_q_w, sw_q_b, sw_k_w, u_buf);
  k_seqw<<<LSEQ, 256, 0, stream>>>(msa_n, u_buf, sw);
  k_bias<<<LL/256, 256, 0, stream>>>(pair, lpg, lpb, wb, bias);
  k_projf<<<dim3(NL/64), 256, 0, stream>>>(msa_n, WTall, qb, kb, gbuf, VT, sw, bg);
  k_scores<<<dim3(3,3,32), 256, 0, stream>>>(qb, kb, scores);
  k_softmax<<<NH*LSEQ, 128, 0, stream>>>(scores, bias, Pb);
  k_pv<<<dim3(64,3,NH), 256, 0, stream>>>(VT, Pb, gbuf, attnout);
  k_final<<<dim3(NL/64), 256, 0, stream>>>(attnout, WOT, bo, out);
}